// Round 3
// baseline (676.946 us; speedup 1.0000x reference)
//
#include <hip/hip_runtime.h>

// B=1, E=4096, H=32, KVH=8, S=2048, HD=128, KVE=1024. GQA: q head h -> kv head h%8.

typedef unsigned short u16;
typedef unsigned int u32;
typedef __attribute__((ext_vector_type(8))) short bf16x8;   // MFMA A/B frag (4 VGPR)
typedef __attribute__((ext_vector_type(4))) float f32x4;    // MFMA C/D frag

__device__ __forceinline__ u16 f2b(float f){
  union { float f; u32 u; } v; v.f = f;
  u32 r = (v.u + 0x7FFFu + ((v.u >> 16) & 1u)) >> 16;  // RNE
  return (u16)r;
}
__device__ __forceinline__ float b2f(u16 b){
  union { u32 u; float f; } v; v.u = ((u32)b) << 16;
  return v.f;
}

// async global->LDS, 16B per lane. LDS dest = wave-uniform base + lane*16.
__device__ __forceinline__ void gld16(const void* g, void* l){
  __builtin_amdgcn_global_load_lds((const __attribute__((address_space(1))) u32*)g,
                                   (__attribute__((address_space(3))) u32*)l, 16, 0, 0);
}

// ---------------------------------------------------------------------------
// fp32 -> bf16 weight conversion
// ---------------------------------------------------------------------------
__global__ __launch_bounds__(256) void cvt_w(const float* __restrict__ src,
                                             u16* __restrict__ dst, int n4)
{
  int i = blockIdx.x * 256 + threadIdx.x;
  if (i < n4){
    float4 v = *(const float4*)&src[(size_t)i * 4];
    ushort4 o; o.x = f2b(v.x); o.y = f2b(v.y); o.z = f2b(v.z); o.w = f2b(v.w);
    *(ushort4*)&dst[(size_t)i * 4] = o;
  }
}

// ---------------------------------------------------------------------------
// transpose X (4096 c x 2048 s, fp32) -> XT (2048 s x 4096 c, bf16)
// ---------------------------------------------------------------------------
__global__ __launch_bounds__(256) void transpose_x(const float* __restrict__ X,
                                                   u16* __restrict__ XT)
{
  __shared__ float lds[64][65];
  const int c0 = blockIdx.x * 64, s0 = blockIdx.y * 64;
  const int tid = threadIdx.x;
  {
    const int sg = tid & 15, cl = tid >> 4;
#pragma unroll
    for (int p = 0; p < 4; ++p){
      int c = cl + p * 16;
      float4 v = *(const float4*)&X[(size_t)(c0 + c) * 2048 + s0 + sg * 4];
      lds[sg*4+0][c] = v.x; lds[sg*4+1][c] = v.y;
      lds[sg*4+2][c] = v.z; lds[sg*4+3][c] = v.w;
    }
  }
  __syncthreads();
  {
    const int cg = tid & 15, sl = tid >> 4;
#pragma unroll
    for (int p = 0; p < 4; ++p){
      int s = sl + p * 16;
      ushort4 o;
      o.x = f2b(lds[s][cg*4+0]); o.y = f2b(lds[s][cg*4+1]);
      o.z = f2b(lds[s][cg*4+2]); o.w = f2b(lds[s][cg*4+3]);
      *(ushort4*)&XT[(size_t)(s0 + s) * 4096 + c0 + cg * 4] = o;
    }
  }
}

// ---------------------------------------------------------------------------
// OLD GEMM (m97 structure) -- kept only for the small-workspace fallback path.
// ---------------------------------------------------------------------------
template<int EPI, int ABF>
__global__ __launch_bounds__(256) void gemm2(
    const u16* __restrict__ W0, const u16* __restrict__ W1, const u16* __restrict__ W2,
    const float* __restrict__ F0, const float* __restrict__ F1, const float* __restrict__ F2,
    const u16* __restrict__ B,
    const float* __restrict__ bias0, const float* __restrict__ bias2,
    u16* __restrict__ QTo, u16* __restrict__ KTo, u16* __restrict__ Vno,
    float* __restrict__ OUT)
{
  const int K = 4096;
  const int m0 = blockIdx.y * 128, n0 = blockIdx.x * 128;

  const u16* A16; const float* Af; int mA;
  if (EPI == 0){
    if (m0 < 4096)      { A16 = W0; Af = F0; mA = m0; }
    else if (m0 < 5120) { A16 = W1; Af = F1; mA = m0 - 4096; }
    else                { A16 = W2; Af = F2; mA = m0 - 5120; }
  } else { A16 = W0; Af = F0; mA = m0; }

  __shared__ __align__(16) u16 As[128 * 32];
  __shared__ __align__(16) u16 Bs[128 * 32];

  const int tid = threadIdx.x, lane = tid & 63, w = tid >> 6;
  const int wm = w >> 1, wn = w & 1, quad = lane >> 4, l15 = lane & 15;

  f32x4 acc[4][4];
#pragma unroll
  for (int mt = 0; mt < 4; ++mt)
#pragma unroll
    for (int nt = 0; nt < 4; ++nt)
      acc[mt][nt] = f32x4{0.f, 0.f, 0.f, 0.f};

  const int r0 = tid >> 2, gs0 = tid & 3;
  const int g0 = gs0 ^ ((r0 >> 1) & 3);
  const int r1 = r0 + 64;

  u16* ldsA0 = As + (size_t)(w * 64) * 8;
  u16* ldsA1 = As + (size_t)(w * 64 + 256) * 8;
  u16* ldsB0 = Bs + (size_t)(w * 64) * 8;
  u16* ldsB1 = Bs + (size_t)(w * 64 + 256) * 8;

  const u16* bsrc0 = &B[(size_t)(n0 + r0) * 4096 + g0 * 8];
  const u16* bsrc1 = &B[(size_t)(n0 + r1) * 4096 + g0 * 8];
  const u16* asrc0 = ABF ? &A16[(size_t)(mA + r0) * 4096 + g0 * 8] : nullptr;
  const u16* asrc1 = ABF ? &A16[(size_t)(mA + r1) * 4096 + g0 * 8] : nullptr;
  const float* afs0 = ABF ? nullptr : &Af[(size_t)(mA + r0) * 4096 + g0 * 8];
  const float* afs1 = ABF ? nullptr : &Af[(size_t)(mA + r1) * 4096 + g0 * 8];

  int aoff[4], boff[4];
#pragma unroll
  for (int mt = 0; mt < 4; ++mt){
    int row = wm * 64 + mt * 16 + l15;
    aoff[mt] = row * 32 + (quad ^ ((row >> 1) & 3)) * 8;
  }
#pragma unroll
  for (int nt = 0; nt < 4; ++nt){
    int row = wn * 64 + nt * 16 + l15;
    boff[nt] = row * 32 + (quad ^ ((row >> 1) & 3)) * 8;
  }

  for (int kt = 0; kt < K / 32; ++kt){
    const int k0 = kt * 32;
    if (ABF){
      gld16(asrc0 + k0, ldsA0);
      gld16(asrc1 + k0, ldsA1);
    } else {
      float4 v0 = *(const float4*)&afs0[k0];
      float4 v1 = *(const float4*)&afs0[k0 + 4];
      float4 v2 = *(const float4*)&afs1[k0];
      float4 v3 = *(const float4*)&afs1[k0 + 4];
      union { u16 u[8]; uint4 q; } p0, p1;
      p0.u[0]=f2b(v0.x); p0.u[1]=f2b(v0.y); p0.u[2]=f2b(v0.z); p0.u[3]=f2b(v0.w);
      p0.u[4]=f2b(v1.x); p0.u[5]=f2b(v1.y); p0.u[6]=f2b(v1.z); p0.u[7]=f2b(v1.w);
      p1.u[0]=f2b(v2.x); p1.u[1]=f2b(v2.y); p1.u[2]=f2b(v2.z); p1.u[3]=f2b(v2.w);
      p1.u[4]=f2b(v3.x); p1.u[5]=f2b(v3.y); p1.u[6]=f2b(v3.z); p1.u[7]=f2b(v3.w);
      *(uint4*)&As[(size_t)tid * 8] = p0.q;
      *(uint4*)&As[(size_t)(tid + 256) * 8] = p1.q;
    }
    gld16(bsrc0 + k0, ldsB0);
    gld16(bsrc1 + k0, ldsB1);
    __syncthreads();

    bf16x8 af[4], bfr[4];
#pragma unroll
    for (int mt = 0; mt < 4; ++mt) af[mt]  = *(const bf16x8*)&As[aoff[mt]];
#pragma unroll
    for (int nt = 0; nt < 4; ++nt) bfr[nt] = *(const bf16x8*)&Bs[boff[nt]];
#pragma unroll
    for (int mt = 0; mt < 4; ++mt)
#pragma unroll
      for (int nt = 0; nt < 4; ++nt)
        acc[mt][nt] = __builtin_amdgcn_mfma_f32_16x16x32_bf16(af[mt], bfr[nt], acc[mt][nt], 0, 0, 0);
    __syncthreads();
  }

  if (EPI == 0){
    if (m0 < 4096){
#pragma unroll
      for (int mt = 0; mt < 4; ++mt){
        int mb = m0 + wm * 64 + mt * 16 + quad * 4;
        float b0 = bias0[mb], b1 = bias0[mb+1], b2 = bias0[mb+2], b3 = bias0[mb+3];
#pragma unroll
        for (int nt = 0; nt < 4; ++nt){
          int n = n0 + wn * 64 + nt * 16 + l15;
          ushort4 o;
          o.x = f2b(acc[mt][nt][0] + b0); o.y = f2b(acc[mt][nt][1] + b1);
          o.z = f2b(acc[mt][nt][2] + b2); o.w = f2b(acc[mt][nt][3] + b3);
          *(ushort4*)&QTo[(size_t)n * 4096 + mb] = o;
        }
      }
    } else if (m0 < 5120){
#pragma unroll
      for (int mt = 0; mt < 4; ++mt){
        int mb = m0 - 4096 + wm * 64 + mt * 16 + quad * 4;
#pragma unroll
        for (int nt = 0; nt < 4; ++nt){
          int n = n0 + wn * 64 + nt * 16 + l15;
          ushort4 o;
          o.x = f2b(acc[mt][nt][0]); o.y = f2b(acc[mt][nt][1]);
          o.z = f2b(acc[mt][nt][2]); o.w = f2b(acc[mt][nt][3]);
          *(ushort4*)&KTo[(size_t)n * 1024 + mb] = o;
        }
      }
    } else {
#pragma unroll
      for (int mt = 0; mt < 4; ++mt)
#pragma unroll
        for (int r = 0; r < 4; ++r){
          int mv = m0 - 5120 + wm * 64 + mt * 16 + quad * 4 + r;
          float bb = bias2[mv];
#pragma unroll
          for (int nt = 0; nt < 4; ++nt){
            int n = n0 + wn * 64 + nt * 16 + l15;
            Vno[(size_t)mv * 2048 + n] = f2b(acc[mt][nt][r] + bb);
          }
        }
    }
  } else {
#pragma unroll
    for (int mt = 0; mt < 4; ++mt)
#pragma unroll
      for (int r = 0; r < 4; ++r){
        int m = m0 + wm * 64 + mt * 16 + quad * 4 + r;
        float bb = bias0[m];
#pragma unroll
        for (int nt = 0; nt < 4; ++nt){
          int n = n0 + wn * 64 + nt * 16 + l15;
          OUT[(size_t)m * 2048 + n] = acc[mt][nt][r] + bb;
        }
      }
  }
}

// ---------------------------------------------------------------------------
// NEW GEMM: 256x256 tile, BK=64 (2 k32 slices = 2 phases), 512 thr / 8 waves
// (2M x 4N), per-wave output 128x64 (acc[8][4]). Counted-vmcnt pipeline:
// tile t+1's 8 loads issued during tile t's phase 0 (s0 chunks first);
// waits alternate vmcnt(8)/vmcnt(4) -- never 0 in the main loop.
// ---------------------------------------------------------------------------
template<int EPI>
__global__ __launch_bounds__(512, 2) void gemm256(
    const u16* __restrict__ W0, const u16* __restrict__ W1, const u16* __restrict__ W2,
    const u16* __restrict__ Bmat,
    const float* __restrict__ bias0, const float* __restrict__ bias2,
    u16* __restrict__ QTo, u16* __restrict__ KTo, u16* __restrict__ Vno,
    float* __restrict__ OUT)
{
  const int NT = 64;                       // K / 64
  const int m0 = blockIdx.y * 256, n0 = blockIdx.x * 256;

  const u16* A16; int mA;
  if (EPI == 0){
    if (m0 < 4096)      { A16 = W0; mA = m0; }
    else if (m0 < 5120) { A16 = W1; mA = m0 - 4096; }
    else                { A16 = W2; mA = m0 - 5120; }
  } else { A16 = W0; mA = m0; }

  __shared__ __align__(16) u16 As[2 * 2 * 8192];   // [buf][slice][256 rows][32 k]  64 KiB
  __shared__ __align__(16) u16 Bs[2 * 2 * 8192];   // 64 KiB

  const int tid = threadIdx.x, lane = tid & 63, w = tid >> 6;
  const int wm = w >> 2, wn = w & 3, quad = lane >> 4, l15 = lane & 15;

  f32x4 acc[8][4];
#pragma unroll
  for (int mt = 0; mt < 8; ++mt)
#pragma unroll
    for (int nt = 0; nt < 4; ++nt)
      acc[mt][nt] = f32x4{0.f, 0.f, 0.f, 0.f};

  // staging geometry: chunk = 128 rows x 32 k = 8KB = 512 lanes x 16B
  const int rowq = tid >> 2;              // 0..127
  const int kg   = (tid & 3) * 8;         // k-granule within slice
  const u16* aG = &A16[(size_t)(mA + rowq) * 4096 + kg];
  const u16* bG = &Bmat[(size_t)(n0 + rowq) * 4096 + kg];
  u16* AsW = As + w * 512;                // wave-uniform LDS dest base
  u16* BsW = Bs + w * 512;

  int aoff[8], boff[4];
#pragma unroll
  for (int mt = 0; mt < 8; ++mt) aoff[mt] = (wm * 128 + mt * 16 + l15) * 32 + quad * 8;
#pragma unroll
  for (int nt = 0; nt < 4; ++nt) boff[nt] = (wn * 64 + nt * 16 + l15) * 32 + quad * 8;

  auto stage8 = [&](int b, int k0){
    u16* Ad = AsW + b * 16384;
    u16* Bd = BsW + b * 16384;
    const u16* as_ = aG + k0;
    const u16* bs_ = bG + k0;
    gld16(as_,                   Ad);                  // A s0 rows 0-127
    gld16(as_ + 128 * 4096,      Ad + 4096);           // A s0 rows 128-255
    gld16(bs_,                   Bd);                  // B s0 rows 0-127
    gld16(bs_ + 128 * 4096,      Bd + 4096);           // B s0 rows 128-255
    gld16(as_ + 32,              Ad + 8192);           // A s1
    gld16(as_ + 32 + 128 * 4096, Ad + 8192 + 4096);
    gld16(bs_ + 32,              Bd + 8192);           // B s1
    gld16(bs_ + 32 + 128 * 4096, Bd + 8192 + 4096);
  };

  stage8(0, 0);
  asm volatile("s_waitcnt vmcnt(4)" ::: "memory");
  __builtin_amdgcn_s_barrier();
  __builtin_amdgcn_sched_barrier(0);

#pragma unroll 1
  for (int t = 0; t < NT; ++t){
    const int buf = t & 1;
    const u16* Asl = As + buf * 16384;
    const u16* Bsl = Bs + buf * 16384;

    // ---- phase 0: k-slice 0; prefetch tile t+1 under the MFMAs ----
    {
      bf16x8 af[8], bf[4];
#pragma unroll
      for (int mt = 0; mt < 8; ++mt) af[mt] = *(const bf16x8*)&Asl[aoff[mt]];
#pragma unroll
      for (int nt = 0; nt < 4; ++nt) bf[nt] = *(const bf16x8*)&Bsl[boff[nt]];
      if (t + 1 < NT) stage8((t + 1) & 1, (t + 1) * 64);
      __builtin_amdgcn_s_setprio(1);
#pragma unroll
      for (int mt = 0; mt < 8; ++mt)
#pragma unroll
        for (int nt = 0; nt < 4; ++nt)
          acc[mt][nt] = __builtin_amdgcn_mfma_f32_16x16x32_bf16(af[mt], bf[nt], acc[mt][nt], 0, 0, 0);
      __builtin_amdgcn_s_setprio(0);
      if (t + 1 < NT) { asm volatile("s_waitcnt vmcnt(8)" ::: "memory"); }
      else            { asm volatile("s_waitcnt vmcnt(0)" ::: "memory"); }
      __builtin_amdgcn_s_barrier();
      __builtin_amdgcn_sched_barrier(0);
    }
    // ---- phase 1: k-slice 1 ----
    {
      bf16x8 af[8], bf[4];
#pragma unroll
      for (int mt = 0; mt < 8; ++mt) af[mt] = *(const bf16x8*)&Asl[8192 + aoff[mt]];
#pragma unroll
      for (int nt = 0; nt < 4; ++nt) bf[nt] = *(const bf16x8*)&Bsl[8192 + boff[nt]];
      __builtin_amdgcn_s_setprio(1);
#pragma unroll
      for (int mt = 0; mt < 8; ++mt)
#pragma unroll
        for (int nt = 0; nt < 4; ++nt)
          acc[mt][nt] = __builtin_amdgcn_mfma_f32_16x16x32_bf16(af[mt], bf[nt], acc[mt][nt], 0, 0, 0);
      __builtin_amdgcn_s_setprio(0);
      if (t + 1 < NT) { asm volatile("s_waitcnt vmcnt(4)" ::: "memory"); }
      __builtin_amdgcn_s_barrier();
      __builtin_amdgcn_sched_barrier(0);
    }
  }

  if (EPI == 0){
    if (m0 < 4096){                 // Q -> QT[s][o] transposed, + bq
#pragma unroll
      for (int mt = 0; mt < 8; ++mt){
        int mb = m0 + wm * 128 + mt * 16 + quad * 4;
        float b0 = bias0[mb], b1 = bias0[mb+1], b2 = bias0[mb+2], b3 = bias0[mb+3];
#pragma unroll
        for (int nt = 0; nt < 4; ++nt){
          int n = n0 + wn * 64 + nt * 16 + l15;
          ushort4 o;
          o.x = f2b(acc[mt][nt][0] + b0); o.y = f2b(acc[mt][nt][1] + b1);
          o.z = f2b(acc[mt][nt][2] + b2); o.w = f2b(acc[mt][nt][3] + b3);
          *(ushort4*)&QTo[(size_t)n * 4096 + mb] = o;
        }
      }
    } else if (m0 < 5120){          // K -> KT[s][kc] transposed
#pragma unroll
      for (int mt = 0; mt < 8; ++mt){
        int mb = m0 - 4096 + wm * 128 + mt * 16 + quad * 4;
#pragma unroll
        for (int nt = 0; nt < 4; ++nt){
          int n = n0 + wn * 64 + nt * 16 + l15;
          ushort4 o;
          o.x = f2b(acc[mt][nt][0]); o.y = f2b(acc[mt][nt][1]);
          o.z = f2b(acc[mt][nt][2]); o.w = f2b(acc[mt][nt][3]);
          *(ushort4*)&KTo[(size_t)n * 1024 + mb] = o;
        }
      }
    } else {                        // V -> Vn[kc][s] natural, + bv
#pragma unroll
      for (int mt = 0; mt < 8; ++mt)
#pragma unroll
        for (int r = 0; r < 4; ++r){
          int mv = m0 - 5120 + wm * 128 + mt * 16 + quad * 4 + r;
          float bb = bias2[mv];
#pragma unroll
          for (int nt = 0; nt < 4; ++nt){
            int n = n0 + wn * 64 + nt * 16 + l15;
            Vno[(size_t)mv * 2048 + n] = f2b(acc[mt][nt][r] + bb);
          }
        }
    }
  } else {
#pragma unroll
    for (int mt = 0; mt < 8; ++mt)
#pragma unroll
      for (int r = 0; r < 4; ++r){
        int m = m0 + wm * 128 + mt * 16 + quad * 4 + r;
        float bb = bias0[m];
#pragma unroll
        for (int nt = 0; nt < 4; ++nt){
          int n = n0 + wn * 64 + nt * 16 + l15;
          OUT[(size_t)m * 2048 + n] = acc[mt][nt][r] + bb;
        }
      }
  }
}

// ---------------------------------------------------------------------------
// RoPE in-place; Q pre-scaled by softmax_scale * log2(e).
// ---------------------------------------------------------------------------
__global__ __launch_bounds__(256) void rope_kernel(u16* __restrict__ QT,
                                                   u16* __restrict__ KT,
                                                   const float* __restrict__ cosp,
                                                   const float* __restrict__ sinp)
{
  const float qscale = 0.08838834764831845f * 1.4426950408889634f;
  int gid = blockIdx.x * 256 + threadIdx.x;
  const int NQ = 2048 * 32 * 64;
  if (gid < NQ){
    int c = gid & 63, hh = (gid >> 6) & 31, s = gid >> 11;
    size_t base = (size_t)s * 4096 + hh * 128 + c;
    float x1 = b2f(QT[base]), x2 = b2f(QT[base + 64]);
    float c1 = cosp[c * 2048 + s],        s1 = sinp[c * 2048 + s];
    float c2 = cosp[(c + 64) * 2048 + s], s2 = sinp[(c + 64) * 2048 + s];
    QT[base]      = f2b((x1 * c1 - x2 * s1) * qscale);
    QT[base + 64] = f2b((x2 * c2 + x1 * s2) * qscale);
  } else {
    int g = gid - NQ;
    int c = g & 63, hh = (g >> 6) & 7, s = g >> 9;
    size_t base = (size_t)s * 1024 + hh * 128 + c;
    float x1 = b2f(KT[base]), x2 = b2f(KT[base + 64]);
    float c1 = cosp[c * 2048 + s],        s1 = sinp[c * 2048 + s];
    float c2 = cosp[(c + 64) * 2048 + s], s2 = sinp[(c + 64) * 2048 + s];
    KT[base]      = f2b(x1 * c1 - x2 * s1);
    KT[base + 64] = f2b(x2 * c2 + x1 * s2);
  }
}

// ---------------------------------------------------------------------------
// Flash attention v4: 512 blocks (32 heads x 16), 4 waves, ONE q-tile per
// wave. Block Y handles tiles {2q, 2q+1, 62-2q, 63-2q}, q = Y<8 ? Y : 23-Y
// (so co-resident block pairs on a CU have ~constant combined extent).
// 2 blocks/CU resident (LDS 57KB, VGPR<=256) -> 2 waves/SIMD latency hiding.
// K double-buffered via global_load_lds, V single-buffered (barrier B).
// ---------------------------------------------------------------------------
__global__ __launch_bounds__(256, 1) void attn4(const u16* __restrict__ QT,
                                                const u16* __restrict__ KT,
                                                const u16* __restrict__ Vn,
                                                u16* __restrict__ AT)
{
  const int h = blockIdx.x;          // 0..31
  const int Y = blockIdx.y;          // 0..15
  const int q = (Y < 8) ? Y : 23 - Y;   // 0..15, pairing for CU balance
  const int kvh = h & 7;
  const int tid = threadIdx.x;
  const int w = tid >> 6, lane = tid & 63;
  const int quad = lane >> 4, l15 = lane & 15;

  // wave w owns tile t: {2q, 2q+1, 62-2q, 63-2q}
  const int t = (w < 2) ? (2 * q + w) : (62 - 2 * q + (w - 2));
  const int e  = t >> 1;             // last compute j-tile for this wave
  const int i0 = t * 32;
  const int U  = 32 - q;             // staged j-tiles (covers max e in block)

  __shared__ __align__(16) u16 Ks[2][64 * 128];  // [j][c] swizzled, 32 KB
  __shared__ __align__(16) u16 Vs[128 * 64];     // [c][j] swizzled, 16 KB
  __shared__ __align__(16) u16 Ps[4][16][64];    // wave-private, swizzled, 8 KB

  // Q A-frags (Q pre-scaled): A[m=l15][k=quad*8+j]
  bf16x8 qa[2][4];
#pragma unroll
  for (int mt = 0; mt < 2; ++mt)
#pragma unroll
    for (int kc = 0; kc < 4; ++kc)
      qa[mt][kc] = *(const bf16x8*)&QT[(size_t)(i0 + mt * 16 + l15) * 4096
                                       + h * 128 + kc * 32 + quad * 8];

  f32x4 o[2][9];
#pragma unroll
  for (int mt = 0; mt < 2; ++mt)
#pragma unroll
    for (int ct = 0; ct < 9; ++ct)
      o[mt][ct] = f32x4{0.f, 0.f, 0.f, 0.f};

  bf16x8 ones;
#pragma unroll
  for (int z = 0; z < 8; ++z) ones[z] = (short)0x3F80;  // bf16 1.0

  const int krl = lane >> 4, kgl = lane & 15;   // K staging: 4 rows x 16 granules
  const int vrl = lane >> 3, vgl = lane & 7;    // V staging: 8 rows x 8 granules

  auto stageK = [&](int buf, int j0){
#pragma unroll
    for (int qq = 0; qq < 4; ++qq){
      int r = w * 16 + qq * 4 + krl;
      gld16(&KT[(size_t)(j0 + r) * 1024 + kvh * 128 + ((kgl ^ (r & 7)) * 8)],
            &Ks[buf][(size_t)(w * 16 + qq * 4) * 128]);
    }
  };
  auto stageV = [&](int j0){
#pragma unroll
    for (int qq = 0; qq < 4; ++qq){
      int r = w * 32 + qq * 8 + vrl;
      gld16(&Vn[(size_t)(kvh * 128 + r) * 2048 + j0 + ((vgl ^ (r & 7)) * 8)],
            &Vs[(size_t)(w * 32 + qq * 8) * 64]);
    }
  };

  stageK(0, 0);
  for (int u = 0; u < U; ++u){
    __syncthreads();                                   // A: Ks[u&1] ready, Vs free
    if (u + 1 < U) stageK((u + 1) & 1, (u + 1) * 64);
    stageV(u * 64);

    const int j0 = u * 64;
    const bool act = (u <= e);
    const u16* Kb = &Ks[u & 1][0];

    f32x4 s[2][4];
    bf16x8 pa[2][2];
    if (act){
#pragma unroll
      for (int mt = 0; mt < 2; ++mt)
#pragma unroll
        for (int nt = 0; nt < 4; ++nt)
          s[mt][nt] = f32x4{0.f, 0.f, 0.f, 0.f};
#pragma unroll
      for (int nt = 0; nt < 4; ++nt){
        bf16x8 kb[4];
#pragma unroll
        for (int kc = 0; kc < 4; ++kc){
          int row = nt * 16 + l15;
          kb[kc] = *(const bf16x8*)&Kb[row * 128 + (((kc * 4 + quad) ^ (row & 7)) * 8)];
        }
#pragma unroll
        for (int kc = 0; kc < 4; ++kc){
          s[0][nt] = __builtin_amdgcn_mfma_f32_16x16x32_bf16(qa[0][kc], kb[kc], s[0][nt], 0, 0, 0);
          s[1][nt] = __builtin_amdgcn_mfma_f32_16x16x32_bf16(qa[1][kc], kb[kc], s[1][nt], 0, 0, 0);
        }
      }
      // softmax: S (C-layout) -> exp2 -> Ps -> pa (A-layout) + rowsum
      const bool maskit = (u == e);
#pragma unroll
      for (int mt = 0; mt < 2; ++mt){
#pragma unroll
        for (int nt = 0; nt < 4; ++nt)
#pragma unroll
          for (int r = 0; r < 4; ++r){
            float pv = exp2f(fminf(s[mt][nt][r], 60.0f));
            if (maskit && (j0 + nt * 16 + l15 > i0 + mt * 16 + quad * 4 + r)) pv = 0.0f;
            int col = nt * 16 + l15, rowp = quad * 4 + r;
            Ps[w][rowp][((col >> 3) ^ (rowp & 7)) * 8 + (col & 7)] = f2b(pv);
          }
#pragma unroll
        for (int kc = 0; kc < 2; ++kc){
          pa[mt][kc] = *(const bf16x8*)&Ps[w][l15][((kc * 4 + quad) ^ (l15 & 7)) * 8];
          o[mt][8] = __builtin_amdgcn_mfma_f32_16x16x32_bf16(pa[mt][kc], ones, o[mt][8], 0, 0, 0);
        }
      }
    }
    __syncthreads();                                   // B: Vs ready

    if (act){
#pragma unroll
      for (int ct = 0; ct < 8; ++ct)
#pragma unroll
        for (int kc = 0; kc < 2; ++kc){
          int row = ct * 16 + l15;
          bf16x8 vb = *(const bf16x8*)&Vs[row * 64 + (((kc * 4 + quad) ^ (row & 7)) * 8)];
          o[0][ct] = __builtin_amdgcn_mfma_f32_16x16x32_bf16(pa[0][kc], vb, o[0][ct], 0, 0, 0);
          o[1][ct] = __builtin_amdgcn_mfma_f32_16x16x32_bf16(pa[1][kc], vb, o[1][ct], 0, 0, 0);
        }
      if (u == e){
        // epilogue: normalize rows by rowsum and store
#pragma unroll
        for (int mt = 0; mt < 2; ++mt){
          float rinv[4];
#pragma unroll
          for (int r = 0; r < 4; ++r) rinv[r] = 1.0f / o[mt][8][r];
#pragma unroll
          for (int ct = 0; ct < 8; ++ct)
#pragma unroll
            for (int r = 0; r < 4; ++r){
              int i = i0 + mt * 16 + quad * 4 + r;
              AT[(size_t)i * 4096 + h * 128 + ct * 16 + l15] = f2b(o[mt][ct][r] * rinv[r]);
            }
        }
      }
    }
  }
}

// ---------------------------------------------------------------------------
extern "C" void kernel_launch(void* const* d_in, const int* in_sizes, int n_in,
                              void* d_out, int out_size, void* d_ws, size_t ws_size,
                              hipStream_t stream)
{
  const float* X    = (const float*)d_in[0];
  const float* cosp = (const float*)d_in[1];
  const float* sinp = (const float*)d_in[2];
  const float* wq   = (const float*)d_in[3];
  const float* bq   = (const float*)d_in[4];
  const float* wk   = (const float*)d_in[5];
  const float* wv   = (const float*)d_in[6];
  const float* bv   = (const float*)d_in[7];
  const float* wo   = (const float*)d_in[8];
  const float* bo   = (const float*)d_in[9];
  float* out = (float*)d_out;

  char* ws = (char*)d_ws;
  const size_t MB = 1u << 20;

  if (ws_size >= 88 * MB){
    u16* W16Q = (u16*)(ws);                 // 32 MiB
    u16* W16K = (u16*)(ws + 32 * MB);       //  8 MiB
    u16* W16V = (u16*)(ws + 40 * MB);       //  8 MiB
    u16* XT   = (u16*)(ws + 48 * MB);       // 16 MiB
    u16* QT   = (u16*)(ws + 64 * MB);       // 16 MiB
    u16* KT   = (u16*)(ws + 80 * MB);       //  4 MiB
    u16* Vn   = (u16*)(ws + 84 * MB);       //  4 MiB
    u16* AT   = (u16*)(ws + 48 * MB);       // alias XT (dead after QKV gemm)
    u16* WO16 = (u16*)(ws);                 // alias W16Q (dead after QKV gemm)

    cvt_w<<<16384, 256, 0, stream>>>(wq, W16Q, 4194304);
    cvt_w<<< 4096, 256, 0, stream>>>(wk, W16K, 1048576);
    cvt_w<<< 4096, 256, 0, stream>>>(wv, W16V, 1048576);
    transpose_x<<<dim3(64, 32), 256, 0, stream>>>(X, XT);
    gemm256<0><<<dim3(8, 24), 512, 0, stream>>>(W16Q, W16K, W16V, XT,
                                                bq, bv, QT, KT, Vn, nullptr);
    cvt_w<<<16384, 256, 0, stream>>>(wo, WO16, 4194304);
    rope_kernel<<<20480, 256, 0, stream>>>(QT, KT, cosp, sinp);
    attn4<<<dim3(32, 16), 256, 0, stream>>>(QT, KT, Vn, AT);
    gemm256<1><<<dim3(8, 16), 512, 0, stream>>>(WO16, nullptr, nullptr, AT,
                                                bo, nullptr, nullptr, nullptr, nullptr, out);
  } else {
    u16* XT = (u16*)(ws);
    u16* QT = (u16*)(ws + 16 * MB);
    u16* KT = (u16*)(ws + 32 * MB);
    u16* Vn = (u16*)(ws + 36 * MB);
    u16* AT = (u16*)(ws + 40 * MB);

    transpose_x<<<dim3(64, 32), 256, 0, stream>>>(X, XT);
    gemm2<0,0><<<dim3(16, 48), 256, 0, stream>>>(nullptr, nullptr, nullptr, wq, wk, wv,
                                                 XT, bq, bv, QT, KT, Vn, nullptr);
    rope_kernel<<<20480, 256, 0, stream>>>(QT, KT, cosp, sinp);
    attn4<<<dim3(32, 16), 256, 0, stream>>>(QT, KT, Vn, AT);
    gemm2<1,0><<<dim3(16, 32), 256, 0, stream>>>(nullptr, nullptr, nullptr, wo, nullptr, nullptr,
                                                 AT, bo, nullptr, nullptr, nullptr, nullptr, out);
  }
}

// Round 4
// 598.515 us; speedup vs baseline: 1.1310x; 1.1310x over previous
//
#include <hip/hip_runtime.h>

// B=1, E=4096, H=32, KVH=8, S=2048, HD=128, KVE=1024. GQA: q head h -> kv head h%8.

typedef unsigned short u16;
typedef unsigned int u32;
typedef __attribute__((ext_vector_type(8))) short bf16x8;   // MFMA A/B frag (4 VGPR)
typedef __attribute__((ext_vector_type(4))) float f32x4;    // MFMA C/D frag

__device__ __forceinline__ u16 f2b(float f){
  union { float f; u32 u; } v; v.f = f;
  u32 r = (v.u + 0x7FFFu + ((v.u >> 16) & 1u)) >> 16;  // RNE
  return (u16)r;
}
__device__ __forceinline__ float b2f(u16 b){
  union { u32 u; float f; } v; v.u = ((u32)b) << 16;
  return v.f;
}

// async global->LDS, 16B per lane. LDS dest = wave-uniform base + lane*16.
__device__ __forceinline__ void gld16(const void* g, void* l){
  __builtin_amdgcn_global_load_lds((const __attribute__((address_space(1))) u32*)g,
                                   (__attribute__((address_space(3))) u32*)l, 16, 0, 0);
}

// ---------------------------------------------------------------------------
// fp32 -> bf16 weight conversion
// ---------------------------------------------------------------------------
__global__ __launch_bounds__(256) void cvt_w(const float* __restrict__ src,
                                             u16* __restrict__ dst, int n4)
{
  int i = blockIdx.x * 256 + threadIdx.x;
  if (i < n4){
    float4 v = *(const float4*)&src[(size_t)i * 4];
    ushort4 o; o.x = f2b(v.x); o.y = f2b(v.y); o.z = f2b(v.z); o.w = f2b(v.w);
    *(ushort4*)&dst[(size_t)i * 4] = o;
  }
}

// ---------------------------------------------------------------------------
// transpose X (4096 c x 2048 s, fp32) -> XT (2048 s x 4096 c, bf16)
// ---------------------------------------------------------------------------
__global__ __launch_bounds__(256) void transpose_x(const float* __restrict__ X,
                                                   u16* __restrict__ XT)
{
  __shared__ float lds[64][65];
  const int c0 = blockIdx.x * 64, s0 = blockIdx.y * 64;
  const int tid = threadIdx.x;
  {
    const int sg = tid & 15, cl = tid >> 4;
#pragma unroll
    for (int p = 0; p < 4; ++p){
      int c = cl + p * 16;
      float4 v = *(const float4*)&X[(size_t)(c0 + c) * 2048 + s0 + sg * 4];
      lds[sg*4+0][c] = v.x; lds[sg*4+1][c] = v.y;
      lds[sg*4+2][c] = v.z; lds[sg*4+3][c] = v.w;
    }
  }
  __syncthreads();
  {
    const int cg = tid & 15, sl = tid >> 4;
#pragma unroll
    for (int p = 0; p < 4; ++p){
      int s = sl + p * 16;
      ushort4 o;
      o.x = f2b(lds[s][cg*4+0]); o.y = f2b(lds[s][cg*4+1]);
      o.z = f2b(lds[s][cg*4+2]); o.w = f2b(lds[s][cg*4+3]);
      *(ushort4*)&XT[(size_t)(s0 + s) * 4096 + c0 + cg * 4] = o;
    }
  }
}

// ---------------------------------------------------------------------------
// OLD GEMM (m97 structure) -- kept only for the small-workspace fallback path.
// ---------------------------------------------------------------------------
template<int EPI, int ABF>
__global__ __launch_bounds__(256) void gemm2(
    const u16* __restrict__ W0, const u16* __restrict__ W1, const u16* __restrict__ W2,
    const float* __restrict__ F0, const float* __restrict__ F1, const float* __restrict__ F2,
    const u16* __restrict__ B,
    const float* __restrict__ bias0, const float* __restrict__ bias2,
    u16* __restrict__ QTo, u16* __restrict__ KTo, u16* __restrict__ Vno,
    float* __restrict__ OUT)
{
  const int K = 4096;
  const int m0 = blockIdx.y * 128, n0 = blockIdx.x * 128;

  const u16* A16; const float* Af; int mA;
  if (EPI == 0){
    if (m0 < 4096)      { A16 = W0; Af = F0; mA = m0; }
    else if (m0 < 5120) { A16 = W1; Af = F1; mA = m0 - 4096; }
    else                { A16 = W2; Af = F2; mA = m0 - 5120; }
  } else { A16 = W0; Af = F0; mA = m0; }

  __shared__ __align__(16) u16 As[128 * 32];
  __shared__ __align__(16) u16 Bs[128 * 32];

  const int tid = threadIdx.x, lane = tid & 63, w = tid >> 6;
  const int wm = w >> 1, wn = w & 1, quad = lane >> 4, l15 = lane & 15;

  f32x4 acc[4][4];
#pragma unroll
  for (int mt = 0; mt < 4; ++mt)
#pragma unroll
    for (int nt = 0; nt < 4; ++nt)
      acc[mt][nt] = f32x4{0.f, 0.f, 0.f, 0.f};

  const int r0 = tid >> 2, gs0 = tid & 3;
  const int g0 = gs0 ^ ((r0 >> 1) & 3);
  const int r1 = r0 + 64;

  u16* ldsA0 = As + (size_t)(w * 64) * 8;
  u16* ldsA1 = As + (size_t)(w * 64 + 256) * 8;
  u16* ldsB0 = Bs + (size_t)(w * 64) * 8;
  u16* ldsB1 = Bs + (size_t)(w * 64 + 256) * 8;

  const u16* bsrc0 = &B[(size_t)(n0 + r0) * 4096 + g0 * 8];
  const u16* bsrc1 = &B[(size_t)(n0 + r1) * 4096 + g0 * 8];
  const u16* asrc0 = ABF ? &A16[(size_t)(mA + r0) * 4096 + g0 * 8] : nullptr;
  const u16* asrc1 = ABF ? &A16[(size_t)(mA + r1) * 4096 + g0 * 8] : nullptr;
  const float* afs0 = ABF ? nullptr : &Af[(size_t)(mA + r0) * 4096 + g0 * 8];
  const float* afs1 = ABF ? nullptr : &Af[(size_t)(mA + r1) * 4096 + g0 * 8];

  int aoff[4], boff[4];
#pragma unroll
  for (int mt = 0; mt < 4; ++mt){
    int row = wm * 64 + mt * 16 + l15;
    aoff[mt] = row * 32 + (quad ^ ((row >> 1) & 3)) * 8;
  }
#pragma unroll
  for (int nt = 0; nt < 4; ++nt){
    int row = wn * 64 + nt * 16 + l15;
    boff[nt] = row * 32 + (quad ^ ((row >> 1) & 3)) * 8;
  }

  for (int kt = 0; kt < K / 32; ++kt){
    const int k0 = kt * 32;
    if (ABF){
      gld16(asrc0 + k0, ldsA0);
      gld16(asrc1 + k0, ldsA1);
    } else {
      float4 v0 = *(const float4*)&afs0[k0];
      float4 v1 = *(const float4*)&afs0[k0 + 4];
      float4 v2 = *(const float4*)&afs1[k0];
      float4 v3 = *(const float4*)&afs1[k0 + 4];
      union { u16 u[8]; uint4 q; } p0, p1;
      p0.u[0]=f2b(v0.x); p0.u[1]=f2b(v0.y); p0.u[2]=f2b(v0.z); p0.u[3]=f2b(v0.w);
      p0.u[4]=f2b(v1.x); p0.u[5]=f2b(v1.y); p0.u[6]=f2b(v1.z); p0.u[7]=f2b(v1.w);
      p1.u[0]=f2b(v2.x); p1.u[1]=f2b(v2.y); p1.u[2]=f2b(v2.z); p1.u[3]=f2b(v2.w);
      p1.u[4]=f2b(v3.x); p1.u[5]=f2b(v3.y); p1.u[6]=f2b(v3.z); p1.u[7]=f2b(v3.w);
      *(uint4*)&As[(size_t)tid * 8] = p0.q;
      *(uint4*)&As[(size_t)(tid + 256) * 8] = p1.q;
    }
    gld16(bsrc0 + k0, ldsB0);
    gld16(bsrc1 + k0, ldsB1);
    __syncthreads();

    bf16x8 af[4], bfr[4];
#pragma unroll
    for (int mt = 0; mt < 4; ++mt) af[mt]  = *(const bf16x8*)&As[aoff[mt]];
#pragma unroll
    for (int nt = 0; nt < 4; ++nt) bfr[nt] = *(const bf16x8*)&Bs[boff[nt]];
#pragma unroll
    for (int mt = 0; mt < 4; ++mt)
#pragma unroll
      for (int nt = 0; nt < 4; ++nt)
        acc[mt][nt] = __builtin_amdgcn_mfma_f32_16x16x32_bf16(af[mt], bfr[nt], acc[mt][nt], 0, 0, 0);
    __syncthreads();
  }

  if (EPI == 0){
    if (m0 < 4096){
#pragma unroll
      for (int mt = 0; mt < 4; ++mt){
        int mb = m0 + wm * 64 + mt * 16 + quad * 4;
        float b0 = bias0[mb], b1 = bias0[mb+1], b2 = bias0[mb+2], b3 = bias0[mb+3];
#pragma unroll
        for (int nt = 0; nt < 4; ++nt){
          int n = n0 + wn * 64 + nt * 16 + l15;
          ushort4 o;
          o.x = f2b(acc[mt][nt][0] + b0); o.y = f2b(acc[mt][nt][1] + b1);
          o.z = f2b(acc[mt][nt][2] + b2); o.w = f2b(acc[mt][nt][3] + b3);
          *(ushort4*)&QTo[(size_t)n * 4096 + mb] = o;
        }
      }
    } else if (m0 < 5120){
#pragma unroll
      for (int mt = 0; mt < 4; ++mt){
        int mb = m0 - 4096 + wm * 64 + mt * 16 + quad * 4;
#pragma unroll
        for (int nt = 0; nt < 4; ++nt){
          int n = n0 + wn * 64 + nt * 16 + l15;
          ushort4 o;
          o.x = f2b(acc[mt][nt][0]); o.y = f2b(acc[mt][nt][1]);
          o.z = f2b(acc[mt][nt][2]); o.w = f2b(acc[mt][nt][3]);
          *(ushort4*)&KTo[(size_t)n * 1024 + mb] = o;
        }
      }
    } else {
#pragma unroll
      for (int mt = 0; mt < 4; ++mt)
#pragma unroll
        for (int r = 0; r < 4; ++r){
          int mv = m0 - 5120 + wm * 64 + mt * 16 + quad * 4 + r;
          float bb = bias2[mv];
#pragma unroll
          for (int nt = 0; nt < 4; ++nt){
            int n = n0 + wn * 64 + nt * 16 + l15;
            Vno[(size_t)mv * 2048 + n] = f2b(acc[mt][nt][r] + bb);
          }
        }
    }
  } else {
#pragma unroll
    for (int mt = 0; mt < 4; ++mt)
#pragma unroll
      for (int r = 0; r < 4; ++r){
        int m = m0 + wm * 64 + mt * 16 + quad * 4 + r;
        float bb = bias0[m];
#pragma unroll
        for (int nt = 0; nt < 4; ++nt){
          int n = n0 + wn * 64 + nt * 16 + l15;
          OUT[(size_t)m * 2048 + n] = acc[mt][nt][r] + bb;
        }
      }
  }
}

// ---------------------------------------------------------------------------
// GEMM: BM x 256 tile, BK=64 (2 k32 slices = 2 phases), 512 thr / 8 waves
// (2M x 4N), per-wave output (BM/2) x 64. Counted-vmcnt pipeline; XOR granule
// swizzle ((row>>1)&3) applied BOTH on the pre-swizzled global source and the
// LDS read offset (rule: both-sides-or-neither with global_load_lds).
// C[m][n] = sum_k A[m][k]*B[n][k], K=4096.
// ---------------------------------------------------------------------------
template<int EPI, int BM>
__global__ __launch_bounds__(512, 2) void gemm256(
    const u16* __restrict__ W0, const u16* __restrict__ W1, const u16* __restrict__ W2,
    const u16* __restrict__ Bmat,
    const float* __restrict__ bias0, const float* __restrict__ bias2,
    u16* __restrict__ QTo, u16* __restrict__ KTo, u16* __restrict__ Vno,
    float* __restrict__ OUT)
{
  const int NT = 64;                       // K / 64
  const int m0 = blockIdx.y * BM, n0 = blockIdx.x * 256;
  constexpr int MT    = BM / 32;           // acc m-tiles per wave (8 / 4)
  constexpr int ACH   = BM / 128;          // A chunks per slice (2 / 1)
  constexpr int SLICE = BM * 32;           // A slice elems
  constexpr int ABUF  = 2 * SLICE;         // A buf elems

  const u16* A16; int mA;
  if (EPI == 0){
    if (m0 < 4096)      { A16 = W0; mA = m0; }
    else if (m0 < 5120) { A16 = W1; mA = m0 - 4096; }
    else                { A16 = W2; mA = m0 - 5120; }
  } else { A16 = W0; mA = m0; }

  __shared__ __align__(16) u16 As[2 * ABUF];       // 64 KB (BM=256) / 32 KB (128)
  __shared__ __align__(16) u16 Bs[2 * 2 * 8192];   // 64 KB

  const int tid = threadIdx.x, lane = tid & 63, w = tid >> 6;
  const int wm = w >> 2, wn = w & 3, quad = lane >> 4, l15 = lane & 15;

  f32x4 acc[MT][4];
#pragma unroll
  for (int mt = 0; mt < MT; ++mt)
#pragma unroll
    for (int nt = 0; nt < 4; ++nt)
      acc[mt][nt] = f32x4{0.f, 0.f, 0.f, 0.f};

  // staging geometry: chunk = 128 rows x 32 k = 8KB = 512 lanes x 16B.
  // source granule pre-swizzled so LDS(row, g) = Global(row, g ^ ((row>>1)&3)).
  const int rowq = tid >> 2;
  const int kgA  = ((tid & 3) ^ ((rowq >> 1) & 3)) * 8;
  const u16* aG = &A16[(size_t)(mA + rowq) * 4096 + kgA];
  const u16* bG = &Bmat[(size_t)(n0 + rowq) * 4096 + kgA];
  u16* AsW = As + w * 512;                // wave-uniform LDS dest base
  u16* BsW = Bs + w * 512;

  int aoff[MT], boff[4];
#pragma unroll
  for (int mt = 0; mt < MT; ++mt){
    int row = wm * (BM / 2) + mt * 16 + l15;
    aoff[mt] = row * 32 + ((quad ^ ((row >> 1) & 3)) * 8);
  }
#pragma unroll
  for (int nt = 0; nt < 4; ++nt){
    int row = wn * 64 + nt * 16 + l15;
    boff[nt] = row * 32 + ((quad ^ ((row >> 1) & 3)) * 8);
  }

  // stage one K-tile into buf b; per-slice order {A(xACH), B, B}.
  auto stageT = [&](int b, int k0){
    u16* Ad = AsW + b * ABUF;
    u16* Bd = BsW + b * 16384;
    const u16* as_ = aG + k0;
    const u16* bs_ = bG + k0;
    gld16(as_, Ad);
    if constexpr (ACH == 2) gld16(as_ + 128 * 4096, Ad + 4096);
    gld16(bs_, Bd);
    gld16(bs_ + 128 * 4096, Bd + 4096);
    gld16(as_ + 32, Ad + SLICE);
    if constexpr (ACH == 2) gld16(as_ + 32 + 128 * 4096, Ad + SLICE + 4096);
    gld16(bs_ + 32, Bd + 8192);
    gld16(bs_ + 32 + 128 * 4096, Bd + 8192 + 4096);
  };

  // prologue: tile 0 in flight; wait for its s0 only (s1 half may fly).
  stageT(0, 0);
  if constexpr (BM == 256) asm volatile("s_waitcnt vmcnt(4)" ::: "memory");
  else                     asm volatile("s_waitcnt vmcnt(3)" ::: "memory");
  __builtin_amdgcn_s_barrier();
  __builtin_amdgcn_sched_barrier(0);

#pragma unroll 1
  for (int t = 0; t < NT; ++t){
    const int buf = t & 1;
    const u16* Asl = As + buf * ABUF;
    const u16* Bsl = Bs + buf * 16384;

    // ---- phase 0: k-slice 0; prefetch tile t+1 under the MFMAs ----
    {
      bf16x8 af[MT], bf[4];
#pragma unroll
      for (int mt = 0; mt < MT; ++mt) af[mt] = *(const bf16x8*)&Asl[aoff[mt]];
#pragma unroll
      for (int nt = 0; nt < 4; ++nt) bf[nt] = *(const bf16x8*)&Bsl[boff[nt]];
      if (t + 1 < NT) stageT((t + 1) & 1, (t + 1) * 64);
      __builtin_amdgcn_s_setprio(1);
#pragma unroll
      for (int mt = 0; mt < MT; ++mt)
#pragma unroll
        for (int nt = 0; nt < 4; ++nt)
          acc[mt][nt] = __builtin_amdgcn_mfma_f32_16x16x32_bf16(af[mt], bf[nt], acc[mt][nt], 0, 0, 0);
      __builtin_amdgcn_s_setprio(0);
      if (t + 1 < NT){
        if constexpr (BM == 256) asm volatile("s_waitcnt vmcnt(8)" ::: "memory");
        else                     asm volatile("s_waitcnt vmcnt(6)" ::: "memory");
      } else {
        asm volatile("s_waitcnt vmcnt(0)" ::: "memory");
      }
      __builtin_amdgcn_s_barrier();
      __builtin_amdgcn_sched_barrier(0);
    }
    // ---- phase 1: k-slice 1 ----
    {
      bf16x8 af[MT], bf[4];
#pragma unroll
      for (int mt = 0; mt < MT; ++mt) af[mt] = *(const bf16x8*)&Asl[SLICE + aoff[mt]];
#pragma unroll
      for (int nt = 0; nt < 4; ++nt) bf[nt] = *(const bf16x8*)&Bsl[8192 + boff[nt]];
      __builtin_amdgcn_s_setprio(1);
#pragma unroll
      for (int mt = 0; mt < MT; ++mt)
#pragma unroll
        for (int nt = 0; nt < 4; ++nt)
          acc[mt][nt] = __builtin_amdgcn_mfma_f32_16x16x32_bf16(af[mt], bf[nt], acc[mt][nt], 0, 0, 0);
      __builtin_amdgcn_s_setprio(0);
      if (t + 1 < NT){
        if constexpr (BM == 256) asm volatile("s_waitcnt vmcnt(4)" ::: "memory");
        else                     asm volatile("s_waitcnt vmcnt(3)" ::: "memory");
      }
      __builtin_amdgcn_s_barrier();
      __builtin_amdgcn_sched_barrier(0);
    }
  }

  if (EPI == 0){
    if (m0 < 4096){                 // Q -> QT[s][o] transposed, + bq
#pragma unroll
      for (int mt = 0; mt < MT; ++mt){
        int mb = m0 + wm * (BM / 2) + mt * 16 + quad * 4;
        float b0 = bias0[mb], b1 = bias0[mb+1], b2 = bias0[mb+2], b3 = bias0[mb+3];
#pragma unroll
        for (int nt = 0; nt < 4; ++nt){
          int n = n0 + wn * 64 + nt * 16 + l15;
          ushort4 o;
          o.x = f2b(acc[mt][nt][0] + b0); o.y = f2b(acc[mt][nt][1] + b1);
          o.z = f2b(acc[mt][nt][2] + b2); o.w = f2b(acc[mt][nt][3] + b3);
          *(ushort4*)&QTo[(size_t)n * 4096 + mb] = o;
        }
      }
    } else if (m0 < 5120){          // K -> KT[s][kc] transposed
#pragma unroll
      for (int mt = 0; mt < MT; ++mt){
        int mb = m0 - 4096 + wm * (BM / 2) + mt * 16 + quad * 4;
#pragma unroll
        for (int nt = 0; nt < 4; ++nt){
          int n = n0 + wn * 64 + nt * 16 + l15;
          ushort4 o;
          o.x = f2b(acc[mt][nt][0]); o.y = f2b(acc[mt][nt][1]);
          o.z = f2b(acc[mt][nt][2]); o.w = f2b(acc[mt][nt][3]);
          *(ushort4*)&KTo[(size_t)n * 1024 + mb] = o;
        }
      }
    } else {                        // V -> Vn[kc][s] natural, + bv
#pragma unroll
      for (int mt = 0; mt < MT; ++mt)
#pragma unroll
        for (int r = 0; r < 4; ++r){
          int mv = m0 - 5120 + wm * (BM / 2) + mt * 16 + quad * 4 + r;
          float bb = bias2[mv];
#pragma unroll
          for (int nt = 0; nt < 4; ++nt){
            int n = n0 + wn * 64 + nt * 16 + l15;
            Vno[(size_t)mv * 2048 + n] = f2b(acc[mt][nt][r] + bb);
          }
        }
    }
  } else {
#pragma unroll
    for (int mt = 0; mt < MT; ++mt)
#pragma unroll
      for (int r = 0; r < 4; ++r){
        int m = m0 + wm * (BM / 2) + mt * 16 + quad * 4 + r;
        float bb = bias0[m];
#pragma unroll
        for (int nt = 0; nt < 4; ++nt){
          int n = n0 + wn * 64 + nt * 16 + l15;
          OUT[(size_t)m * 2048 + n] = acc[mt][nt][r] + bb;
        }
      }
  }
}

// ---------------------------------------------------------------------------
// RoPE in-place; Q pre-scaled by softmax_scale * log2(e).
// ---------------------------------------------------------------------------
__global__ __launch_bounds__(256) void rope_kernel(u16* __restrict__ QT,
                                                   u16* __restrict__ KT,
                                                   const float* __restrict__ cosp,
                                                   const float* __restrict__ sinp)
{
  const float qscale = 0.08838834764831845f * 1.4426950408889634f;
  int gid = blockIdx.x * 256 + threadIdx.x;
  const int NQ = 2048 * 32 * 64;
  if (gid < NQ){
    int c = gid & 63, hh = (gid >> 6) & 31, s = gid >> 11;
    size_t base = (size_t)s * 4096 + hh * 128 + c;
    float x1 = b2f(QT[base]), x2 = b2f(QT[base + 64]);
    float c1 = cosp[c * 2048 + s],        s1 = sinp[c * 2048 + s];
    float c2 = cosp[(c + 64) * 2048 + s], s2 = sinp[(c + 64) * 2048 + s];
    QT[base]      = f2b((x1 * c1 - x2 * s1) * qscale);
    QT[base + 64] = f2b((x2 * c2 + x1 * s2) * qscale);
  } else {
    int g = gid - NQ;
    int c = g & 63, hh = (g >> 6) & 7, s = g >> 9;
    size_t base = (size_t)s * 1024 + hh * 128 + c;
    float x1 = b2f(KT[base]), x2 = b2f(KT[base + 64]);
    float c1 = cosp[c * 2048 + s],        s1 = sinp[c * 2048 + s];
    float c2 = cosp[(c + 64) * 2048 + s], s2 = sinp[(c + 64) * 2048 + s];
    KT[base]      = f2b(x1 * c1 - x2 * s1);
    KT[base + 64] = f2b(x2 * c2 + x1 * s2);
  }
}

// ---------------------------------------------------------------------------
// Flash attention v5: 256 blocks (32 heads x 8 groups) x 512 threads (8
// waves) -- forced 8 waves/CU (2/SIMD), no CP-packing dependence. Block
// (h, g) owns tiles {8g..8g+7}, one per wave; U = 4g+4, so all 8 waves stay
// compute-active for ~all iterations (balanced SIMD-mates). stageV issued
// BEFORE stageK(u+1); barrier B waits vmcnt(2) so next-tile K loads stay in
// flight under PV (counted-vmcnt). K double-buffered, V single-buffered.
// ---------------------------------------------------------------------------
__global__ __launch_bounds__(512, 2) void attn5(const u16* __restrict__ QT,
                                                const u16* __restrict__ KT,
                                                const u16* __restrict__ Vn,
                                                u16* __restrict__ AT)
{
  const int h = blockIdx.x;          // 0..31
  const int g = blockIdx.y;          // 0..7
  const int kvh = h & 7;
  const int tid = threadIdx.x;
  const int w = tid >> 6, lane = tid & 63;
  const int quad = lane >> 4, l15 = lane & 15;

  const int t = 8 * g + w;           // 0..63, wave's q-tile
  const int e = t >> 1;              // last compute j-tile
  const int i0 = t * 32;
  const int U = 4 * g + 4;           // staged j-tiles (= max e in block + 1)

  __shared__ __align__(16) u16 Ks[2][64 * 128];  // [j][c] swizzled, 32 KB
  __shared__ __align__(16) u16 Vs[128 * 64];     // [c][j] swizzled, 16 KB
  __shared__ __align__(16) u16 Ps[8][16][64];    // wave-private, swizzled, 16 KB

  // Q A-frags (Q pre-scaled): A[m=l15][k=quad*8+j]
  bf16x8 qa[2][4];
#pragma unroll
  for (int mt = 0; mt < 2; ++mt)
#pragma unroll
    for (int kc = 0; kc < 4; ++kc)
      qa[mt][kc] = *(const bf16x8*)&QT[(size_t)(i0 + mt * 16 + l15) * 4096
                                       + h * 128 + kc * 32 + quad * 8];

  f32x4 o[2][9];
#pragma unroll
  for (int mt = 0; mt < 2; ++mt)
#pragma unroll
    for (int ct = 0; ct < 9; ++ct)
      o[mt][ct] = f32x4{0.f, 0.f, 0.f, 0.f};

  bf16x8 ones;
#pragma unroll
  for (int z = 0; z < 8; ++z) ones[z] = (short)0x3F80;  // bf16 1.0

  const int krl = lane >> 4, kgl = lane & 15;   // K staging: 4 rows x 16 granules
  const int vrl = lane >> 3, vgl = lane & 7;    // V staging: 8 rows x 8 granules

  // K j-tile = 64 rows x 128c: wave w stages rows [w*8, w*8+8) (2 x gld16).
  auto stageK = [&](int buf, int j0){
#pragma unroll
    for (int qq = 0; qq < 2; ++qq){
      int r = w * 8 + qq * 4 + krl;
      gld16(&KT[(size_t)(j0 + r) * 1024 + kvh * 128 + ((kgl ^ (r & 7)) * 8)],
            &Ks[buf][(size_t)(w * 8 + qq * 4) * 128]);
    }
  };
  // V j-tile = 128 rows(c) x 64j: wave w stages rows [w*16, w*16+16).
  auto stageV = [&](int j0){
#pragma unroll
    for (int qq = 0; qq < 2; ++qq){
      int r = w * 16 + qq * 8 + vrl;
      gld16(&Vn[(size_t)(kvh * 128 + r) * 2048 + j0 + ((vgl ^ (r & 7)) * 8)],
            &Vs[(size_t)(w * 16 + qq * 8) * 64]);
    }
  };

  stageK(0, 0);
  for (int u = 0; u < U; ++u){
    // barrier A: Ks[u&1] landed (only K loads outstanding), Vs free.
    __syncthreads();
    stageV(u * 64);                              // 2 loads (oldest)
    if (u + 1 < U) stageK((u + 1) & 1, (u + 1) * 64);  // 2 loads (newest)

    const int j0 = u * 64;
    const bool act = (u <= e);
    const u16* Kb = &Ks[u & 1][0];

    f32x4 s[2][4];
    bf16x8 pa[2][2];
    if (act){
#pragma unroll
      for (int mt = 0; mt < 2; ++mt)
#pragma unroll
        for (int nt = 0; nt < 4; ++nt)
          s[mt][nt] = f32x4{0.f, 0.f, 0.f, 0.f};
#pragma unroll
      for (int nt = 0; nt < 4; ++nt){
        bf16x8 kb[4];
#pragma unroll
        for (int kc = 0; kc < 4; ++kc){
          int row = nt * 16 + l15;
          kb[kc] = *(const bf16x8*)&Kb[row * 128 + (((kc * 4 + quad) ^ (row & 7)) * 8)];
        }
        __builtin_amdgcn_s_setprio(1);
#pragma unroll
        for (int kc = 0; kc < 4; ++kc){
          s[0][nt] = __builtin_amdgcn_mfma_f32_16x16x32_bf16(qa[0][kc], kb[kc], s[0][nt], 0, 0, 0);
          s[1][nt] = __builtin_amdgcn_mfma_f32_16x16x32_bf16(qa[1][kc], kb[kc], s[1][nt], 0, 0, 0);
        }
        __builtin_amdgcn_s_setprio(0);
      }
      // softmax: S (C-layout) -> exp2 -> Ps -> pa (A-layout) + rowsum
      const bool maskit = (u == e);
#pragma unroll
      for (int mt = 0; mt < 2; ++mt){
#pragma unroll
        for (int nt = 0; nt < 4; ++nt)
#pragma unroll
          for (int r = 0; r < 4; ++r){
            float pv = exp2f(fminf(s[mt][nt][r], 60.0f));
            if (maskit && (j0 + nt * 16 + l15 > i0 + mt * 16 + quad * 4 + r)) pv = 0.0f;
            int col = nt * 16 + l15, rowp = quad * 4 + r;
            Ps[w][rowp][((col >> 3) ^ (rowp & 7)) * 8 + (col & 7)] = f2b(pv);
          }
#pragma unroll
        for (int kc = 0; kc < 2; ++kc){
          pa[mt][kc] = *(const bf16x8*)&Ps[w][l15][((kc * 4 + quad) ^ (l15 & 7)) * 8];
          o[mt][8] = __builtin_amdgcn_mfma_f32_16x16x32_bf16(pa[mt][kc], ones, o[mt][8], 0, 0, 0);
        }
      }
    }
    // barrier B: Vs ready; keep next-tile K loads (2 newest) in flight.
    if (u + 1 < U) asm volatile("s_waitcnt vmcnt(2)" ::: "memory");
    else           asm volatile("s_waitcnt vmcnt(0)" ::: "memory");
    __builtin_amdgcn_s_barrier();
    __builtin_amdgcn_sched_barrier(0);

    if (act){
#pragma unroll
      for (int ct = 0; ct < 8; ++ct){
#pragma unroll
        for (int kc = 0; kc < 2; ++kc){
          int row = ct * 16 + l15;
          bf16x8 vb = *(const bf16x8*)&Vs[row * 64 + (((kc * 4 + quad) ^ (row & 7)) * 8)];
          __builtin_amdgcn_s_setprio(1);
          o[0][ct] = __builtin_amdgcn_mfma_f32_16x16x32_bf16(pa[0][kc], vb, o[0][ct], 0, 0, 0);
          o[1][ct] = __builtin_amdgcn_mfma_f32_16x16x32_bf16(pa[1][kc], vb, o[1][ct], 0, 0, 0);
          __builtin_amdgcn_s_setprio(0);
        }
      }
      if (u == e){
        // epilogue: normalize rows by rowsum and store
#pragma unroll
        for (int mt = 0; mt < 2; ++mt){
          float rinv[4];
#pragma unroll
          for (int r = 0; r < 4; ++r) rinv[r] = 1.0f / o[mt][8][r];
#pragma unroll
          for (int ct = 0; ct < 8; ++ct)
#pragma unroll
            for (int r = 0; r < 4; ++r){
              int i = i0 + mt * 16 + quad * 4 + r;
              AT[(size_t)i * 4096 + h * 128 + ct * 16 + l15] = f2b(o[mt][ct][r] * rinv[r]);
            }
        }
      }
    }
  }
}

// ---------------------------------------------------------------------------
extern "C" void kernel_launch(void* const* d_in, const int* in_sizes, int n_in,
                              void* d_out, int out_size, void* d_ws, size_t ws_size,
                              hipStream_t stream)
{
  const float* X    = (const float*)d_in[0];
  const float* cosp = (const float*)d_in[1];
  const float* sinp = (const float*)d_in[2];
  const float* wq   = (const float*)d_in[3];
  const float* bq   = (const float*)d_in[4];
  const float* wk   = (const float*)d_in[5];
  const float* wv   = (const float*)d_in[6];
  const float* bv   = (const float*)d_in[7];
  const float* wo   = (const float*)d_in[8];
  const float* bo   = (const float*)d_in[9];
  float* out = (float*)d_out;

  char* ws = (char*)d_ws;
  const size_t MB = 1u << 20;

  if (ws_size >= 88 * MB){
    u16* W16Q = (u16*)(ws);                 // 32 MiB
    u16* W16K = (u16*)(ws + 32 * MB);       //  8 MiB
    u16* W16V = (u16*)(ws + 40 * MB);       //  8 MiB
    u16* XT   = (u16*)(ws + 48 * MB);       // 16 MiB
    u16* QT   = (u16*)(ws + 64 * MB);       // 16 MiB
    u16* KT   = (u16*)(ws + 80 * MB);       //  4 MiB
    u16* Vn   = (u16*)(ws + 84 * MB);       //  4 MiB
    u16* AT   = (u16*)(ws + 48 * MB);       // alias XT (dead after QKV gemm)
    u16* WO16 = (u16*)(ws);                 // alias W16Q (dead after QKV gemm)

    cvt_w<<<16384, 256, 0, stream>>>(wq, W16Q, 4194304);
    cvt_w<<< 4096, 256, 0, stream>>>(wk, W16K, 1048576);
    cvt_w<<< 4096, 256, 0, stream>>>(wv, W16V, 1048576);
    transpose_x<<<dim3(64, 32), 256, 0, stream>>>(X, XT);
    gemm256<0, 256><<<dim3(8, 24), 512, 0, stream>>>(W16Q, W16K, W16V, XT,
                                                     bq, bv, QT, KT, Vn, nullptr);
    cvt_w<<<16384, 256, 0, stream>>>(wo, WO16, 4194304);
    rope_kernel<<<20480, 256, 0, stream>>>(QT, KT, cosp, sinp);
    attn5<<<dim3(32, 8), 512, 0, stream>>>(QT, KT, Vn, AT);
    gemm256<1, 128><<<dim3(8, 32), 512, 0, stream>>>(WO16, nullptr, nullptr, AT,
                                                     bo, nullptr, nullptr, nullptr, nullptr, out);
  } else {
    u16* XT = (u16*)(ws);
    u16* QT = (u16*)(ws + 16 * MB);
    u16* KT = (u16*)(ws + 32 * MB);
    u16* Vn = (u16*)(ws + 36 * MB);
    u16* AT = (u16*)(ws + 40 * MB);

    transpose_x<<<dim3(64, 32), 256, 0, stream>>>(X, XT);
    gemm2<0,0><<<dim3(16, 48), 256, 0, stream>>>(nullptr, nullptr, nullptr, wq, wk, wv,
                                                 XT, bq, bv, QT, KT, Vn, nullptr);
    rope_kernel<<<20480, 256, 0, stream>>>(QT, KT, cosp, sinp);
    attn5<<<dim3(32, 8), 512, 0, stream>>>(QT, KT, Vn, AT);
    gemm2<1,0><<<dim3(16, 32), 256, 0, stream>>>(nullptr, nullptr, nullptr, wo, nullptr, nullptr,
                                                 AT, bo, nullptr, nullptr, nullptr, nullptr, out);
  }
}

// Round 5
// 592.144 us; speedup vs baseline: 1.1432x; 1.0108x over previous
//
#include <hip/hip_runtime.h>

// B=1, E=4096, H=32, KVH=8, S=2048, HD=128, KVE=1024. GQA: q head h -> kv head h%8.

typedef unsigned short u16;
typedef unsigned int u32;
typedef __attribute__((ext_vector_type(8))) short bf16x8;   // MFMA A/B frag (4 VGPR)
typedef __attribute__((ext_vector_type(4))) float f32x4;    // MFMA C/D frag

__device__ __forceinline__ u16 f2b(float f){
  union { float f; u32 u; } v; v.f = f;
  u32 r = (v.u + 0x7FFFu + ((v.u >> 16) & 1u)) >> 16;  // RNE
  return (u16)r;
}
__device__ __forceinline__ float b2f(u16 b){
  union { u32 u; float f; } v; v.u = ((u32)b) << 16;
  return v.f;
}

// async global->LDS, 16B per lane. LDS dest = wave-uniform base + lane*16.
__device__ __forceinline__ void gld16(const void* g, void* l){
  __builtin_amdgcn_global_load_lds((const __attribute__((address_space(1))) u32*)g,
                                   (__attribute__((address_space(3))) u32*)l, 16, 0, 0);
}

// ---------------------------------------------------------------------------
// fp32 -> bf16 weight conversion
// ---------------------------------------------------------------------------
__global__ __launch_bounds__(256) void cvt_w(const float* __restrict__ src,
                                             u16* __restrict__ dst, int n4)
{
  int i = blockIdx.x * 256 + threadIdx.x;
  if (i < n4){
    float4 v = *(const float4*)&src[(size_t)i * 4];
    ushort4 o; o.x = f2b(v.x); o.y = f2b(v.y); o.z = f2b(v.z); o.w = f2b(v.w);
    *(ushort4*)&dst[(size_t)i * 4] = o;
  }
}

// ---------------------------------------------------------------------------
// transpose X (4096 c x 2048 s, fp32) -> XT (2048 s x 4096 c, bf16)
// ---------------------------------------------------------------------------
__global__ __launch_bounds__(256) void transpose_x(const float* __restrict__ X,
                                                   u16* __restrict__ XT)
{
  __shared__ float lds[64][65];
  const int c0 = blockIdx.x * 64, s0 = blockIdx.y * 64;
  const int tid = threadIdx.x;
  {
    const int sg = tid & 15, cl = tid >> 4;
#pragma unroll
    for (int p = 0; p < 4; ++p){
      int c = cl + p * 16;
      float4 v = *(const float4*)&X[(size_t)(c0 + c) * 2048 + s0 + sg * 4];
      lds[sg*4+0][c] = v.x; lds[sg*4+1][c] = v.y;
      lds[sg*4+2][c] = v.z; lds[sg*4+3][c] = v.w;
    }
  }
  __syncthreads();
  {
    const int cg = tid & 15, sl = tid >> 4;
#pragma unroll
    for (int p = 0; p < 4; ++p){
      int s = sl + p * 16;
      ushort4 o;
      o.x = f2b(lds[s][cg*4+0]); o.y = f2b(lds[s][cg*4+1]);
      o.z = f2b(lds[s][cg*4+2]); o.w = f2b(lds[s][cg*4+3]);
      *(ushort4*)&XT[(size_t)(s0 + s) * 4096 + c0 + cg * 4] = o;
    }
  }
}

// ---------------------------------------------------------------------------
// OLD GEMM (m97 structure) -- kept only for the small-workspace fallback path.
// ---------------------------------------------------------------------------
template<int EPI, int ABF>
__global__ __launch_bounds__(256) void gemm2(
    const u16* __restrict__ W0, const u16* __restrict__ W1, const u16* __restrict__ W2,
    const float* __restrict__ F0, const float* __restrict__ F1, const float* __restrict__ F2,
    const u16* __restrict__ B,
    const float* __restrict__ bias0, const float* __restrict__ bias2,
    u16* __restrict__ QTo, u16* __restrict__ KTo, u16* __restrict__ Vno,
    float* __restrict__ OUT)
{
  const int K = 4096;
  const int m0 = blockIdx.y * 128, n0 = blockIdx.x * 128;

  const u16* A16; const float* Af; int mA;
  if (EPI == 0){
    if (m0 < 4096)      { A16 = W0; Af = F0; mA = m0; }
    else if (m0 < 5120) { A16 = W1; Af = F1; mA = m0 - 4096; }
    else                { A16 = W2; Af = F2; mA = m0 - 5120; }
  } else { A16 = W0; Af = F0; mA = m0; }

  __shared__ __align__(16) u16 As[128 * 32];
  __shared__ __align__(16) u16 Bs[128 * 32];

  const int tid = threadIdx.x, lane = tid & 63, w = tid >> 6;
  const int wm = w >> 1, wn = w & 1, quad = lane >> 4, l15 = lane & 15;

  f32x4 acc[4][4];
#pragma unroll
  for (int mt = 0; mt < 4; ++mt)
#pragma unroll
    for (int nt = 0; nt < 4; ++nt)
      acc[mt][nt] = f32x4{0.f, 0.f, 0.f, 0.f};

  const int r0 = tid >> 2, gs0 = tid & 3;
  const int g0 = gs0 ^ ((r0 >> 1) & 3);
  const int r1 = r0 + 64;

  u16* ldsA0 = As + (size_t)(w * 64) * 8;
  u16* ldsA1 = As + (size_t)(w * 64 + 256) * 8;
  u16* ldsB0 = Bs + (size_t)(w * 64) * 8;
  u16* ldsB1 = Bs + (size_t)(w * 64 + 256) * 8;

  const u16* bsrc0 = &B[(size_t)(n0 + r0) * 4096 + g0 * 8];
  const u16* bsrc1 = &B[(size_t)(n0 + r1) * 4096 + g0 * 8];
  const u16* asrc0 = ABF ? &A16[(size_t)(mA + r0) * 4096 + g0 * 8] : nullptr;
  const u16* asrc1 = ABF ? &A16[(size_t)(mA + r1) * 4096 + g0 * 8] : nullptr;
  const float* afs0 = ABF ? nullptr : &Af[(size_t)(mA + r0) * 4096 + g0 * 8];
  const float* afs1 = ABF ? nullptr : &Af[(size_t)(mA + r1) * 4096 + g0 * 8];

  int aoff[4], boff[4];
#pragma unroll
  for (int mt = 0; mt < 4; ++mt){
    int row = wm * 64 + mt * 16 + l15;
    aoff[mt] = row * 32 + (quad ^ ((row >> 1) & 3)) * 8;
  }
#pragma unroll
  for (int nt = 0; nt < 4; ++nt){
    int row = wn * 64 + nt * 16 + l15;
    boff[nt] = row * 32 + (quad ^ ((row >> 1) & 3)) * 8;
  }

  for (int kt = 0; kt < K / 32; ++kt){
    const int k0 = kt * 32;
    if (ABF){
      gld16(asrc0 + k0, ldsA0);
      gld16(asrc1 + k0, ldsA1);
    } else {
      float4 v0 = *(const float4*)&afs0[k0];
      float4 v1 = *(const float4*)&afs0[k0 + 4];
      float4 v2 = *(const float4*)&afs1[k0];
      float4 v3 = *(const float4*)&afs1[k0 + 4];
      union { u16 u[8]; uint4 q; } p0, p1;
      p0.u[0]=f2b(v0.x); p0.u[1]=f2b(v0.y); p0.u[2]=f2b(v0.z); p0.u[3]=f2b(v0.w);
      p0.u[4]=f2b(v1.x); p0.u[5]=f2b(v1.y); p0.u[6]=f2b(v1.z); p0.u[7]=f2b(v1.w);
      p1.u[0]=f2b(v2.x); p1.u[1]=f2b(v2.y); p1.u[2]=f2b(v2.z); p1.u[3]=f2b(v2.w);
      p1.u[4]=f2b(v3.x); p1.u[5]=f2b(v3.y); p1.u[6]=f2b(v3.z); p1.u[7]=f2b(v3.w);
      *(uint4*)&As[(size_t)tid * 8] = p0.q;
      *(uint4*)&As[(size_t)(tid + 256) * 8] = p1.q;
    }
    gld16(bsrc0 + k0, ldsB0);
    gld16(bsrc1 + k0, ldsB1);
    __syncthreads();

    bf16x8 af[4], bfr[4];
#pragma unroll
    for (int mt = 0; mt < 4; ++mt) af[mt]  = *(const bf16x8*)&As[aoff[mt]];
#pragma unroll
    for (int nt = 0; nt < 4; ++nt) bfr[nt] = *(const bf16x8*)&Bs[boff[nt]];
#pragma unroll
    for (int mt = 0; mt < 4; ++mt)
#pragma unroll
      for (int nt = 0; nt < 4; ++nt)
        acc[mt][nt] = __builtin_amdgcn_mfma_f32_16x16x32_bf16(af[mt], bfr[nt], acc[mt][nt], 0, 0, 0);
    __syncthreads();
  }

  if (EPI == 0){
    if (m0 < 4096){
#pragma unroll
      for (int mt = 0; mt < 4; ++mt){
        int mb = m0 + wm * 64 + mt * 16 + quad * 4;
        float b0 = bias0[mb], b1 = bias0[mb+1], b2 = bias0[mb+2], b3 = bias0[mb+3];
#pragma unroll
        for (int nt = 0; nt < 4; ++nt){
          int n = n0 + wn * 64 + nt * 16 + l15;
          ushort4 o;
          o.x = f2b(acc[mt][nt][0] + b0); o.y = f2b(acc[mt][nt][1] + b1);
          o.z = f2b(acc[mt][nt][2] + b2); o.w = f2b(acc[mt][nt][3] + b3);
          *(ushort4*)&QTo[(size_t)n * 4096 + mb] = o;
        }
      }
    } else if (m0 < 5120){
#pragma unroll
      for (int mt = 0; mt < 4; ++mt){
        int mb = m0 - 4096 + wm * 64 + mt * 16 + quad * 4;
#pragma unroll
        for (int nt = 0; nt < 4; ++nt){
          int n = n0 + wn * 64 + nt * 16 + l15;
          ushort4 o;
          o.x = f2b(acc[mt][nt][0]); o.y = f2b(acc[mt][nt][1]);
          o.z = f2b(acc[mt][nt][2]); o.w = f2b(acc[mt][nt][3]);
          *(ushort4*)&KTo[(size_t)n * 1024 + mb] = o;
        }
      }
    } else {
#pragma unroll
      for (int mt = 0; mt < 4; ++mt)
#pragma unroll
        for (int r = 0; r < 4; ++r){
          int mv = m0 - 5120 + wm * 64 + mt * 16 + quad * 4 + r;
          float bb = bias2[mv];
#pragma unroll
          for (int nt = 0; nt < 4; ++nt){
            int n = n0 + wn * 64 + nt * 16 + l15;
            Vno[(size_t)mv * 2048 + n] = f2b(acc[mt][nt][r] + bb);
          }
        }
    }
  } else {
#pragma unroll
    for (int mt = 0; mt < 4; ++mt)
#pragma unroll
      for (int r = 0; r < 4; ++r){
        int m = m0 + wm * 64 + mt * 16 + quad * 4 + r;
        float bb = bias0[m];
#pragma unroll
        for (int nt = 0; nt < 4; ++nt){
          int n = n0 + wn * 64 + nt * 16 + l15;
          OUT[(size_t)m * 2048 + n] = acc[mt][nt][r] + bb;
        }
      }
  }
}

// ---------------------------------------------------------------------------
// GEMM, 4-phase interleaved schedule (T3+T4+T5 port of the m201 template):
// BM x 256 tile, BK=64, 512 thr / 8 waves (2M x 4N), per-wave (BM/2) x 64.
// Per phase: {4-8 ds_read_b128, stage gld16s, barrier, lgkmcnt(0), setprio,
// 16(8) MFMA, setprio, [vmcnt(N)], barrier}. Stage order per K-tile:
//   BM=256: A-ks0(2), B-ks0(2), A-ks1(2), B-ks1(2)  -> vmcnt(4) at ph1/ph3
//   BM=128: A-ks0,B-ks0lo | B-ks0hi | A-ks1,B-ks1lo | B-ks1hi -> vmcnt(3)
// Consumers run 4(3) units behind the newest loads; vmcnt never 0 mid-loop.
// XOR granule swizzle both-sides (conflict-free, measured 0).
// C[m][n] = sum_k A[m][k]*B[n][k], K=4096.
// ---------------------------------------------------------------------------
template<int EPI, int BM>
__global__ __launch_bounds__(512, 2) void gemm256(
    const u16* __restrict__ W0, const u16* __restrict__ W1, const u16* __restrict__ W2,
    const u16* __restrict__ Bmat,
    const float* __restrict__ bias0, const float* __restrict__ bias2,
    u16* __restrict__ QTo, u16* __restrict__ KTo, u16* __restrict__ Vno,
    float* __restrict__ OUT)
{
  const int NT = 64;                       // K / 64
  const int m0 = blockIdx.y * BM, n0 = blockIdx.x * 256;
  constexpr int MT    = BM / 32;           // acc m-tiles per wave (8 / 4)
  constexpr int SLICE = BM * 32;           // A slice elems
  constexpr int ABUF  = 2 * SLICE;         // A buf elems

  const u16* A16; int mA;
  if (EPI == 0){
    if (m0 < 4096)      { A16 = W0; mA = m0; }
    else if (m0 < 5120) { A16 = W1; mA = m0 - 4096; }
    else                { A16 = W2; mA = m0 - 5120; }
  } else { A16 = W0; mA = m0; }

  __shared__ __align__(16) u16 As[2 * ABUF];       // 64 KB (BM=256) / 32 KB (128)
  __shared__ __align__(16) u16 Bs[2 * 2 * 8192];   // 64 KB

  const int tid = threadIdx.x, lane = tid & 63, w = tid >> 6;
  const int wm = w >> 2, wn = w & 3, quad = lane >> 4, l15 = lane & 15;

  f32x4 acc[MT][4];
#pragma unroll
  for (int mt = 0; mt < MT; ++mt)
#pragma unroll
    for (int nt = 0; nt < 4; ++nt)
      acc[mt][nt] = f32x4{0.f, 0.f, 0.f, 0.f};

  // staging geometry: unit = 128 rows x 32 k = 8KB = 512 lanes x 16B.
  // source granule pre-swizzled so LDS(row, g) = Global(row, g ^ ((row>>1)&3)).
  const int rowq = tid >> 2;
  const int kgA  = ((tid & 3) ^ ((rowq >> 1) & 3)) * 8;
  const u16* aG = &A16[(size_t)(mA + rowq) * 4096 + kgA];
  const u16* bG = &Bmat[(size_t)(n0 + rowq) * 4096 + kgA];
  u16* AsW = As + w * 512;                // wave-uniform LDS dest base
  u16* BsW = Bs + w * 512;

  int aoff[MT], boff[4];
#pragma unroll
  for (int mt = 0; mt < MT; ++mt){
    int row = wm * (BM / 2) + mt * 16 + l15;
    aoff[mt] = row * 32 + ((quad ^ ((row >> 1) & 3)) * 8);
  }
#pragma unroll
  for (int nt = 0; nt < 4; ++nt){
    int row = wn * 64 + nt * 16 + l15;
    boff[nt] = row * 32 + ((quad ^ ((row >> 1) & 3)) * 8);
  }

  // prologue: stage tile 0 in consumer order, wait ks0 units only.
  {
    u16* Ad = AsW; u16* Bd = BsW;
    if constexpr (BM == 256){
      gld16(aG, Ad); gld16(aG + 128 * 4096, Ad + 4096);          // A-ks0
      gld16(bG, Bd); gld16(bG + 128 * 4096, Bd + 4096);          // B-ks0
      gld16(aG + 32, Ad + SLICE); gld16(aG + 32 + 128 * 4096, Ad + SLICE + 4096);
      gld16(bG + 32, Bd + 8192);  gld16(bG + 32 + 128 * 4096, Bd + 8192 + 4096);
      asm volatile("s_waitcnt vmcnt(4)" ::: "memory");
    } else {
      gld16(aG, Ad); gld16(bG, Bd);                               // A-ks0, B-ks0lo
      gld16(bG + 128 * 4096, Bd + 4096);                          // B-ks0hi
      gld16(aG + 32, Ad + SLICE);                                 // A-ks1
      gld16(bG + 32, Bd + 8192);                                  // B-ks1lo
      gld16(bG + 32 + 128 * 4096, Bd + 8192 + 4096);              // B-ks1hi
      asm volatile("s_waitcnt vmcnt(3)" ::: "memory");
    }
  }
  __builtin_amdgcn_s_barrier();
  __builtin_amdgcn_sched_barrier(0);

#pragma unroll 1
  for (int t = 0; t < NT; ++t){
    const int buf = t & 1;
    const u16* Asl = As + buf * ABUF;
    const u16* Bsl = Bs + buf * 16384;
    const int nb = buf ^ 1;
    const bool more = (t + 1 < NT);
    u16* Ad = AsW + nb * ABUF;
    u16* Bd = BsW + nb * 16384;
    const u16* as_ = aG + (t + 1) * 64;
    const u16* bs_ = bG + (t + 1) * 64;

    bf16x8 af[4], bf[4];

    // ---------------- phase 0: ks0, first MFMA quadrant ----------------
#pragma unroll
    for (int i = 0; i < 4; ++i) af[i] = *(const bf16x8*)&Asl[aoff[i]];
    if constexpr (BM == 256){
#pragma unroll
      for (int i = 0; i < 4; ++i) bf[i] = *(const bf16x8*)&Bsl[boff[i]];
      if (more){ gld16(as_, Ad); gld16(as_ + 128 * 4096, Ad + 4096); }
    } else {
      bf[0] = *(const bf16x8*)&Bsl[boff[0]];
      bf[1] = *(const bf16x8*)&Bsl[boff[1]];
      if (more){ gld16(as_, Ad); gld16(bs_, Bd); }
    }
    __builtin_amdgcn_s_barrier();
    asm volatile("s_waitcnt lgkmcnt(0)" ::: "memory");
    __builtin_amdgcn_sched_barrier(0);
    __builtin_amdgcn_s_setprio(1);
    if constexpr (BM == 256){
#pragma unroll
      for (int mt = 0; mt < 4; ++mt)
#pragma unroll
        for (int nt = 0; nt < 4; ++nt)
          acc[mt][nt] = __builtin_amdgcn_mfma_f32_16x16x32_bf16(af[mt], bf[nt], acc[mt][nt], 0, 0, 0);
    } else {
#pragma unroll
      for (int mt = 0; mt < 4; ++mt)
#pragma unroll
        for (int nt = 0; nt < 2; ++nt)
          acc[mt][nt] = __builtin_amdgcn_mfma_f32_16x16x32_bf16(af[mt], bf[nt], acc[mt][nt], 0, 0, 0);
    }
    __builtin_amdgcn_s_setprio(0);
    __builtin_amdgcn_s_barrier();
    __builtin_amdgcn_sched_barrier(0);

    // ---------------- phase 1: ks0, second MFMA quadrant ----------------
    if constexpr (BM == 256){
#pragma unroll
      for (int i = 0; i < 4; ++i) af[i] = *(const bf16x8*)&Asl[aoff[4 + i]];
      if (more){ gld16(bs_, Bd); gld16(bs_ + 128 * 4096, Bd + 4096); }
    } else {
      bf[2] = *(const bf16x8*)&Bsl[boff[2]];
      bf[3] = *(const bf16x8*)&Bsl[boff[3]];
      if (more){ gld16(bs_ + 128 * 4096, Bd + 4096); }
    }
    __builtin_amdgcn_s_barrier();
    asm volatile("s_waitcnt lgkmcnt(0)" ::: "memory");
    __builtin_amdgcn_sched_barrier(0);
    __builtin_amdgcn_s_setprio(1);
    if constexpr (BM == 256){
#pragma unroll
      for (int mt = 0; mt < 4; ++mt)
#pragma unroll
        for (int nt = 0; nt < 4; ++nt)
          acc[4 + mt][nt] = __builtin_amdgcn_mfma_f32_16x16x32_bf16(af[mt], bf[nt], acc[4 + mt][nt], 0, 0, 0);
    } else {
#pragma unroll
      for (int mt = 0; mt < 4; ++mt)
#pragma unroll
        for (int nt = 2; nt < 4; ++nt)
          acc[mt][nt] = __builtin_amdgcn_mfma_f32_16x16x32_bf16(af[mt], bf[nt], acc[mt][nt], 0, 0, 0);
    }
    __builtin_amdgcn_s_setprio(0);
    if (more){
      if constexpr (BM == 256) asm volatile("s_waitcnt vmcnt(4)" ::: "memory");
      else                     asm volatile("s_waitcnt vmcnt(3)" ::: "memory");
    } else {
      asm volatile("s_waitcnt vmcnt(0)" ::: "memory");
    }
    __builtin_amdgcn_s_barrier();
    __builtin_amdgcn_sched_barrier(0);

    // ---------------- phase 2: ks1, first MFMA quadrant ----------------
#pragma unroll
    for (int i = 0; i < 4; ++i) af[i] = *(const bf16x8*)&Asl[SLICE + aoff[i]];
    if constexpr (BM == 256){
#pragma unroll
      for (int i = 0; i < 4; ++i) bf[i] = *(const bf16x8*)&Bsl[8192 + boff[i]];
      if (more){ gld16(as_ + 32, Ad + SLICE); gld16(as_ + 32 + 128 * 4096, Ad + SLICE + 4096); }
    } else {
      bf[0] = *(const bf16x8*)&Bsl[8192 + boff[0]];
      bf[1] = *(const bf16x8*)&Bsl[8192 + boff[1]];
      if (more){ gld16(as_ + 32, Ad + SLICE); gld16(bs_ + 32, Bd + 8192); }
    }
    __builtin_amdgcn_s_barrier();
    asm volatile("s_waitcnt lgkmcnt(0)" ::: "memory");
    __builtin_amdgcn_sched_barrier(0);
    __builtin_amdgcn_s_setprio(1);
    if constexpr (BM == 256){
#pragma unroll
      for (int mt = 0; mt < 4; ++mt)
#pragma unroll
        for (int nt = 0; nt < 4; ++nt)
          acc[mt][nt] = __builtin_amdgcn_mfma_f32_16x16x32_bf16(af[mt], bf[nt], acc[mt][nt], 0, 0, 0);
    } else {
#pragma unroll
      for (int mt = 0; mt < 4; ++mt)
#pragma unroll
        for (int nt = 0; nt < 2; ++nt)
          acc[mt][nt] = __builtin_amdgcn_mfma_f32_16x16x32_bf16(af[mt], bf[nt], acc[mt][nt], 0, 0, 0);
    }
    __builtin_amdgcn_s_setprio(0);
    __builtin_amdgcn_s_barrier();
    __builtin_amdgcn_sched_barrier(0);

    // ---------------- phase 3: ks1, second MFMA quadrant ----------------
    if constexpr (BM == 256){
#pragma unroll
      for (int i = 0; i < 4; ++i) af[i] = *(const bf16x8*)&Asl[SLICE + aoff[4 + i]];
      if (more){ gld16(bs_ + 32, Bd + 8192); gld16(bs_ + 32 + 128 * 4096, Bd + 8192 + 4096); }
    } else {
      bf[2] = *(const bf16x8*)&Bsl[8192 + boff[2]];
      bf[3] = *(const bf16x8*)&Bsl[8192 + boff[3]];
      if (more){ gld16(bs_ + 32 + 128 * 4096, Bd + 8192 + 4096); }
    }
    __builtin_amdgcn_s_barrier();
    asm volatile("s_waitcnt lgkmcnt(0)" ::: "memory");
    __builtin_amdgcn_sched_barrier(0);
    __builtin_amdgcn_s_setprio(1);
    if constexpr (BM == 256){
#pragma unroll
      for (int mt = 0; mt < 4; ++mt)
#pragma unroll
        for (int nt = 0; nt < 4; ++nt)
          acc[4 + mt][nt] = __builtin_amdgcn_mfma_f32_16x16x32_bf16(af[mt], bf[nt], acc[4 + mt][nt], 0, 0, 0);
    } else {
#pragma unroll
      for (int mt = 0; mt < 4; ++mt)
#pragma unroll
        for (int nt = 2; nt < 4; ++nt)
          acc[mt][nt] = __builtin_amdgcn_mfma_f32_16x16x32_bf16(af[mt], bf[nt], acc[mt][nt], 0, 0, 0);
    }
    __builtin_amdgcn_s_setprio(0);
    if (more){
      if constexpr (BM == 256) asm volatile("s_waitcnt vmcnt(4)" ::: "memory");
      else                     asm volatile("s_waitcnt vmcnt(3)" ::: "memory");
    } else {
      asm volatile("s_waitcnt vmcnt(0)" ::: "memory");
    }
    __builtin_amdgcn_s_barrier();
    __builtin_amdgcn_sched_barrier(0);
  }

  if (EPI == 0){
    if (m0 < 4096){                 // Q -> QT[s][o] transposed, + bq
#pragma unroll
      for (int mt = 0; mt < MT; ++mt){
        int mb = m0 + wm * (BM / 2) + mt * 16 + quad * 4;
        float b0 = bias0[mb], b1 = bias0[mb+1], b2 = bias0[mb+2], b3 = bias0[mb+3];
#pragma unroll
        for (int nt = 0; nt < 4; ++nt){
          int n = n0 + wn * 64 + nt * 16 + l15;
          ushort4 o;
          o.x = f2b(acc[mt][nt][0] + b0); o.y = f2b(acc[mt][nt][1] + b1);
          o.z = f2b(acc[mt][nt][2] + b2); o.w = f2b(acc[mt][nt][3] + b3);
          *(ushort4*)&QTo[(size_t)n * 4096 + mb] = o;
        }
      }
    } else if (m0 < 5120){          // K -> KT[s][kc] transposed
#pragma unroll
      for (int mt = 0; mt < MT; ++mt){
        int mb = m0 - 4096 + wm * (BM / 2) + mt * 16 + quad * 4;
#pragma unroll
        for (int nt = 0; nt < 4; ++nt){
          int n = n0 + wn * 64 + nt * 16 + l15;
          ushort4 o;
          o.x = f2b(acc[mt][nt][0]); o.y = f2b(acc[mt][nt][1]);
          o.z = f2b(acc[mt][nt][2]); o.w = f2b(acc[mt][nt][3]);
          *(ushort4*)&KTo[(size_t)n * 1024 + mb] = o;
        }
      }
    } else {                        // V -> Vn[kc][s] natural, + bv
#pragma unroll
      for (int mt = 0; mt < MT; ++mt)
#pragma unroll
        for (int r = 0; r < 4; ++r){
          int mv = m0 - 5120 + wm * (BM / 2) + mt * 16 + quad * 4 + r;
          float bb = bias2[mv];
#pragma unroll
          for (int nt = 0; nt < 4; ++nt){
            int n = n0 + wn * 64 + nt * 16 + l15;
            Vno[(size_t)mv * 2048 + n] = f2b(acc[mt][nt][r] + bb);
          }
        }
    }
  } else {
#pragma unroll
    for (int mt = 0; mt < MT; ++mt)
#pragma unroll
      for (int r = 0; r < 4; ++r){
        int m = m0 + wm * (BM / 2) + mt * 16 + quad * 4 + r;
        float bb = bias0[m];
#pragma unroll
        for (int nt = 0; nt < 4; ++nt){
          int n = n0 + wn * 64 + nt * 16 + l15;
          OUT[(size_t)m * 2048 + n] = acc[mt][nt][r] + bb;
        }
      }
  }
}

// ---------------------------------------------------------------------------
// RoPE in-place; Q pre-scaled by softmax_scale * log2(e).
// ---------------------------------------------------------------------------
__global__ __launch_bounds__(256) void rope_kernel(u16* __restrict__ QT,
                                                   u16* __restrict__ KT,
                                                   const float* __restrict__ cosp,
                                                   const float* __restrict__ sinp)
{
  const float qscale = 0.08838834764831845f * 1.4426950408889634f;
  int gid = blockIdx.x * 256 + threadIdx.x;
  const int NQ = 2048 * 32 * 64;
  if (gid < NQ){
    int c = gid & 63, hh = (gid >> 6) & 31, s = gid >> 11;
    size_t base = (size_t)s * 4096 + hh * 128 + c;
    float x1 = b2f(QT[base]), x2 = b2f(QT[base + 64]);
    float c1 = cosp[c * 2048 + s],        s1 = sinp[c * 2048 + s];
    float c2 = cosp[(c + 64) * 2048 + s], s2 = sinp[(c + 64) * 2048 + s];
    QT[base]      = f2b((x1 * c1 - x2 * s1) * qscale);
    QT[base + 64] = f2b((x2 * c2 + x1 * s2) * qscale);
  } else {
    int g = gid - NQ;
    int c = g & 63, hh = (g >> 6) & 7, s = g >> 9;
    size_t base = (size_t)s * 1024 + hh * 128 + c;
    float x1 = b2f(KT[base]), x2 = b2f(KT[base + 64]);
    float c1 = cosp[c * 2048 + s],        s1 = sinp[c * 2048 + s];
    float c2 = cosp[(c + 64) * 2048 + s], s2 = sinp[(c + 64) * 2048 + s];
    KT[base]      = f2b(x1 * c1 - x2 * s1);
    KT[base + 64] = f2b(x2 * c2 + x1 * s2);
  }
}

// ---------------------------------------------------------------------------
// Flash attention v5: 256 blocks (32 heads x 8 groups) x 512 threads (8
// waves) -- forced 8 waves/CU (2/SIMD). Block (h, g) owns tiles {8g..8g+7},
// one per wave; U = 4g+4. stageV before stageK(u+1); barrier B waits
// vmcnt(2) so next-tile K loads stay in flight under PV.
// ---------------------------------------------------------------------------
__global__ __launch_bounds__(512, 2) void attn5(const u16* __restrict__ QT,
                                                const u16* __restrict__ KT,
                                                const u16* __restrict__ Vn,
                                                u16* __restrict__ AT)
{
  const int h = blockIdx.x;          // 0..31
  const int g = blockIdx.y;          // 0..7
  const int kvh = h & 7;
  const int tid = threadIdx.x;
  const int w = tid >> 6, lane = tid & 63;
  const int quad = lane >> 4, l15 = lane & 15;

  const int t = 8 * g + w;           // 0..63, wave's q-tile
  const int e = t >> 1;              // last compute j-tile
  const int i0 = t * 32;
  const int U = 4 * g + 4;           // staged j-tiles (= max e in block + 1)

  __shared__ __align__(16) u16 Ks[2][64 * 128];  // [j][c] swizzled, 32 KB
  __shared__ __align__(16) u16 Vs[128 * 64];     // [c][j] swizzled, 16 KB
  __shared__ __align__(16) u16 Ps[8][16][64];    // wave-private, swizzled, 16 KB

  // Q A-frags (Q pre-scaled): A[m=l15][k=quad*8+j]
  bf16x8 qa[2][4];
#pragma unroll
  for (int mt = 0; mt < 2; ++mt)
#pragma unroll
    for (int kc = 0; kc < 4; ++kc)
      qa[mt][kc] = *(const bf16x8*)&QT[(size_t)(i0 + mt * 16 + l15) * 4096
                                       + h * 128 + kc * 32 + quad * 8];

  f32x4 o[2][9];
#pragma unroll
  for (int mt = 0; mt < 2; ++mt)
#pragma unroll
    for (int ct = 0; ct < 9; ++ct)
      o[mt][ct] = f32x4{0.f, 0.f, 0.f, 0.f};

  bf16x8 ones;
#pragma unroll
  for (int z = 0; z < 8; ++z) ones[z] = (short)0x3F80;  // bf16 1.0

  const int krl = lane >> 4, kgl = lane & 15;   // K staging: 4 rows x 16 granules
  const int vrl = lane >> 3, vgl = lane & 7;    // V staging: 8 rows x 8 granules

  // K j-tile = 64 rows x 128c: wave w stages rows [w*8, w*8+8) (2 x gld16).
  auto stageK = [&](int buf, int j0){
#pragma unroll
    for (int qq = 0; qq < 2; ++qq){
      int r = w * 8 + qq * 4 + krl;
      gld16(&KT[(size_t)(j0 + r) * 1024 + kvh * 128 + ((kgl ^ (r & 7)) * 8)],
            &Ks[buf][(size_t)(w * 8 + qq * 4) * 128]);
    }
  };
  // V j-tile = 128 rows(c) x 64j: wave w stages rows [w*16, w*16+16).
  auto stageV = [&](int j0){
#pragma unroll
    for (int qq = 0; qq < 2; ++qq){
      int r = w * 16 + qq * 8 + vrl;
      gld16(&Vn[(size_t)(kvh * 128 + r) * 2048 + j0 + ((vgl ^ (r & 7)) * 8)],
            &Vs[(size_t)(w * 16 + qq * 8) * 64]);
    }
  };

  stageK(0, 0);
  for (int u = 0; u < U; ++u){
    // barrier A: Ks[u&1] landed (only K loads outstanding), Vs free.
    __syncthreads();
    stageV(u * 64);                              // 2 loads (oldest)
    if (u + 1 < U) stageK((u + 1) & 1, (u + 1) * 64);  // 2 loads (newest)

    const int j0 = u * 64;
    const bool act = (u <= e);
    const u16* Kb = &Ks[u & 1][0];

    f32x4 s[2][4];
    bf16x8 pa[2][2];
    if (act){
#pragma unroll
      for (int mt = 0; mt < 2; ++mt)
#pragma unroll
        for (int nt = 0; nt < 4; ++nt)
          s[mt][nt] = f32x4{0.f, 0.f, 0.f, 0.f};
#pragma unroll
      for (int nt = 0; nt < 4; ++nt){
        bf16x8 kb[4];
#pragma unroll
        for (int kc = 0; kc < 4; ++kc){
          int row = nt * 16 + l15;
          kb[kc] = *(const bf16x8*)&Kb[row * 128 + (((kc * 4 + quad) ^ (row & 7)) * 8)];
        }
        __builtin_amdgcn_s_setprio(1);
#pragma unroll
        for (int kc = 0; kc < 4; ++kc){
          s[0][nt] = __builtin_amdgcn_mfma_f32_16x16x32_bf16(qa[0][kc], kb[kc], s[0][nt], 0, 0, 0);
          s[1][nt] = __builtin_amdgcn_mfma_f32_16x16x32_bf16(qa[1][kc], kb[kc], s[1][nt], 0, 0, 0);
        }
        __builtin_amdgcn_s_setprio(0);
      }
      // softmax: S (C-layout) -> exp2 -> Ps -> pa (A-layout) + rowsum
      const bool maskit = (u == e);
#pragma unroll
      for (int mt = 0; mt < 2; ++mt){
#pragma unroll
        for (int nt = 0; nt < 4; ++nt)
#pragma unroll
          for (int r = 0; r < 4; ++r){
            float pv = exp2f(fminf(s[mt][nt][r], 60.0f));
            if (maskit && (j0 + nt * 16 + l15 > i0 + mt * 16 + quad * 4 + r)) pv = 0.0f;
            int col = nt * 16 + l15, rowp = quad * 4 + r;
            Ps[w][rowp][((col >> 3) ^ (rowp & 7)) * 8 + (col & 7)] = f2b(pv);
          }
#pragma unroll
        for (int kc = 0; kc < 2; ++kc){
          pa[mt][kc] = *(const bf16x8*)&Ps[w][l15][((kc * 4 + quad) ^ (l15 & 7)) * 8];
          o[mt][8] = __builtin_amdgcn_mfma_f32_16x16x32_bf16(pa[mt][kc], ones, o[mt][8], 0, 0, 0);
        }
      }
    }
    // barrier B: Vs ready; keep next-tile K loads (2 newest) in flight.
    if (u + 1 < U) asm volatile("s_waitcnt vmcnt(2)" ::: "memory");
    else           asm volatile("s_waitcnt vmcnt(0)" ::: "memory");
    __builtin_amdgcn_s_barrier();
    __builtin_amdgcn_sched_barrier(0);

    if (act){
#pragma unroll
      for (int ct = 0; ct < 8; ++ct){
#pragma unroll
        for (int kc = 0; kc < 2; ++kc){
          int row = ct * 16 + l15;
          bf16x8 vb = *(const bf16x8*)&Vs[row * 64 + (((kc * 4 + quad) ^ (row & 7)) * 8)];
          __builtin_amdgcn_s_setprio(1);
          o[0][ct] = __builtin_amdgcn_mfma_f32_16x16x32_bf16(pa[0][kc], vb, o[0][ct], 0, 0, 0);
          o[1][ct] = __builtin_amdgcn_mfma_f32_16x16x32_bf16(pa[1][kc], vb, o[1][ct], 0, 0, 0);
          __builtin_amdgcn_s_setprio(0);
        }
      }
      if (u == e){
        // epilogue: normalize rows by rowsum and store
#pragma unroll
        for (int mt = 0; mt < 2; ++mt){
          float rinv[4];
#pragma unroll
          for (int r = 0; r < 4; ++r) rinv[r] = 1.0f / o[mt][8][r];
#pragma unroll
          for (int ct = 0; ct < 8; ++ct)
#pragma unroll
            for (int r = 0; r < 4; ++r){
              int i = i0 + mt * 16 + quad * 4 + r;
              AT[(size_t)i * 4096 + h * 128 + ct * 16 + l15] = f2b(o[mt][ct][r] * rinv[r]);
            }
        }
      }
    }
  }
}

// ---------------------------------------------------------------------------
extern "C" void kernel_launch(void* const* d_in, const int* in_sizes, int n_in,
                              void* d_out, int out_size, void* d_ws, size_t ws_size,
                              hipStream_t stream)
{
  const float* X    = (const float*)d_in[0];
  const float* cosp = (const float*)d_in[1];
  const float* sinp = (const float*)d_in[2];
  const float* wq   = (const float*)d_in[3];
  const float* bq   = (const float*)d_in[4];
  const float* wk   = (const float*)d_in[5];
  const float* wv   = (const float*)d_in[6];
  const float* bv   = (const float*)d_in[7];
  const float* wo   = (const float*)d_in[8];
  const float* bo   = (const float*)d_in[9];
  float* out = (float*)d_out;

  char* ws = (char*)d_ws;
  const size_t MB = 1u << 20;

  if (ws_size >= 88 * MB){
    u16* W16Q = (u16*)(ws);                 // 32 MiB
    u16* W16K = (u16*)(ws + 32 * MB);       //  8 MiB
    u16* W16V = (u16*)(ws + 40 * MB);       //  8 MiB
    u16* XT   = (u16*)(ws + 48 * MB);       // 16 MiB
    u16* QT   = (u16*)(ws + 64 * MB);       // 16 MiB
    u16* KT   = (u16*)(ws + 80 * MB);       //  4 MiB
    u16* Vn   = (u16*)(ws + 84 * MB);       //  4 MiB
    u16* AT   = (u16*)(ws + 48 * MB);       // alias XT (dead after QKV gemm)
    u16* WO16 = (u16*)(ws);                 // alias W16Q (dead after QKV gemm)

    cvt_w<<<16384, 256, 0, stream>>>(wq, W16Q, 4194304);
    cvt_w<<< 4096, 256, 0, stream>>>(wk, W16K, 1048576);
    cvt_w<<< 4096, 256, 0, stream>>>(wv, W16V, 1048576);
    transpose_x<<<dim3(64, 32), 256, 0, stream>>>(X, XT);
    gemm256<0, 256><<<dim3(8, 24), 512, 0, stream>>>(W16Q, W16K, W16V, XT,
                                                     bq, bv, QT, KT, Vn, nullptr);
    cvt_w<<<16384, 256, 0, stream>>>(wo, WO16, 4194304);
    rope_kernel<<<20480, 256, 0, stream>>>(QT, KT, cosp, sinp);
    attn5<<<dim3(32, 8), 512, 0, stream>>>(QT, KT, Vn, AT);
    gemm256<1, 128><<<dim3(8, 32), 512, 0, stream>>>(WO16, nullptr, nullptr, AT,
                                                     bo, nullptr, nullptr, nullptr, nullptr, out);
  } else {
    u16* XT = (u16*)(ws);
    u16* QT = (u16*)(ws + 16 * MB);
    u16* KT = (u16*)(ws + 32 * MB);
    u16* Vn = (u16*)(ws + 36 * MB);
    u16* AT = (u16*)(ws + 40 * MB);

    transpose_x<<<dim3(64, 32), 256, 0, stream>>>(X, XT);
    gemm2<0,0><<<dim3(16, 48), 256, 0, stream>>>(nullptr, nullptr, nullptr, wq, wk, wv,
                                                 XT, bq, bv, QT, KT, Vn, nullptr);
    rope_kernel<<<20480, 256, 0, stream>>>(QT, KT, cosp, sinp);
    attn5<<<dim3(32, 8), 512, 0, stream>>>(QT, KT, Vn, AT);
    gemm2<1,0><<<dim3(16, 32), 256, 0, stream>>>(nullptr, nullptr, nullptr, wo, nullptr, nullptr,
                                                 AT, bo, nullptr, nullptr, nullptr, nullptr, out);
  }
}